// Round 1
// baseline (659.599 us; speedup 1.0000x reference)
//
#include <hip/hip_runtime.h>
#include <math.h>

#define N_NODES 100000
#define N_EDGES 1600000
#define F_INF   128
#define HIDF    128

typedef __attribute__((ext_vector_type(8)))  short short8;
typedef __attribute__((ext_vector_type(16))) float floatx16;

__device__ __forceinline__ unsigned short f2bf(float f) {
    unsigned u = __float_as_uint(f);
    return (unsigned short)((u + 0x7FFFu + ((u >> 16) & 1u)) >> 16);
}
__device__ __forceinline__ float bf2f(unsigned short h) {
    return __uint_as_float((unsigned)h << 16);
}

// ---------------------------------------------------------------- edge MLP
// MFMA formulation: one wave = 32 edges per iteration (unchanged from prev round).
__global__ __launch_bounds__(256) void k_edge_mlp(
        const float* __restrict__ ea,
        const float* __restrict__ w1, const float* __restrict__ b1,
        const float* __restrict__ w2, const float* __restrict__ b2,
        float* __restrict__ ew) {
    const int lane = threadIdx.x & 63;
    const int cl   = lane & 31;
    const int half = lane >> 5;
    const int wid  = blockIdx.x * (blockDim.x >> 6) + (threadIdx.x >> 6);
    const int nw   = gridDim.x * (blockDim.x >> 6);

    short8 bw[4];
    float  w2c[4];
#pragma unroll
    for (int cb = 0; cb < 4; ++cb) {
        const int n = cb * 32 + cl;
        short8 b;
        if (half == 0) {
#pragma unroll
            for (int j = 0; j < 8; ++j) b[j] = (short)f2bf(w1[j * 128 + n]);
        } else {
            b[0] = (short)f2bf(b1[n]);
#pragma unroll
            for (int j = 1; j < 8; ++j) b[j] = 0;
        }
        bw[cb] = b;
        w2c[cb] = w2[n];
    }
    short8 Abias;
    Abias[0] = (short)0x3F80;
#pragma unroll
    for (int j = 1; j < 8; ++j) Abias[j] = 0;

    floatx16 czero;
#pragma unroll
    for (int r = 0; r < 16; ++r) czero[r] = 0.f;

    const float bias2 = b2[0];

    for (int e0 = wid * 32; e0 < N_EDGES; e0 += nw * 32) {
        short8 Ah;
        if (half == 0) {
            const float4 a0 = *(const float4*)(ea + (size_t)(e0 + cl) * 8);
            const float4 a1 = *(const float4*)(ea + (size_t)(e0 + cl) * 8 + 4);
            Ah[0] = (short)f2bf(a0.x); Ah[1] = (short)f2bf(a0.y);
            Ah[2] = (short)f2bf(a0.z); Ah[3] = (short)f2bf(a0.w);
            Ah[4] = (short)f2bf(a1.x); Ah[5] = (short)f2bf(a1.y);
            Ah[6] = (short)f2bf(a1.z); Ah[7] = (short)f2bf(a1.w);
        } else {
            Ah = Abias;
        }

        float z[16];
#pragma unroll
        for (int r = 0; r < 16; ++r) z[r] = 0.f;

#pragma unroll
        for (int cb = 0; cb < 4; ++cb) {
            floatx16 acc = __builtin_amdgcn_mfma_f32_32x32x16_bf16(Ah, bw[cb], czero, 0, 0, 0);
#pragma unroll
            for (int r = 0; r < 16; ++r)
                z[r] = fmaf(fmaxf(acc[r], 0.f), w2c[cb], z[r]);
        }

#pragma unroll
        for (int m = 1; m <= 16; m <<= 1) {
#pragma unroll
            for (int r = 0; r < 16; ++r) z[r] += __shfl_xor(z[r], m, 64);
        }

        float zz = z[0];
#pragma unroll
        for (int r = 1; r < 16; ++r) zz = (cl == r) ? z[r] : zz;
        if (cl < 16) {
            const int row = (cl & 3) + 8 * (cl >> 2) + 4 * half;
            ew[e0 + row] = 1.f / (1.f + __expf(-(zz + bias2)));
        }
    }
}

// ---------------------------------------------------------------- cast + degree (MERGED)
// The k_deg atomic histogram is a memory-side RMW wall (51.2 MB = 1.6M x 32B
// write-through, VALUBusy 0.4%): hide it under the independent x->bf16 cast.
// 3.2M threads; even-global-id threads each own one edge, so atomic issue is
// spread uniformly across the kernel's lifetime and overlaps the streaming cast.
__global__ void k_cast_deg(const float* __restrict__ x, unsigned short* __restrict__ xb,
                           const int* __restrict__ dst, int* __restrict__ deg,
                           unsigned char* __restrict__ rank) {
    const int gid = blockIdx.x * 256 + threadIdx.x;     // 0 .. 3.2M-1
    const int i = gid * 4;                               // N*128 elems exactly
    const float4 v = *(const float4*)(x + i);
    ushort4 o;
    o.x = f2bf(v.x); o.y = f2bf(v.y); o.z = f2bf(v.z); o.w = f2bf(v.w);
    *(ushort4*)(xb + i) = o;
    if ((gid & 1) == 0) {
        const int e = gid >> 1;                          // covers all 1.6M edges exactly
        rank[e] = (unsigned char)atomicAdd(&deg[dst[e]], 1);
    }
}

// ---------------------------------------------------------------- CSR build (unchanged)
__global__ void k_scan1(const int* __restrict__ deg, int* __restrict__ incl,
                        int* __restrict__ bsum) {
    __shared__ int sm[1024];
    const int tid = threadIdx.x;
    const int gi  = blockIdx.x * 1024 + tid;
    int v = (gi < N_NODES) ? deg[gi] : 0;
    sm[tid] = v;
    __syncthreads();
    for (int off = 1; off < 1024; off <<= 1) {
        int t = (tid >= off) ? sm[tid - off] : 0;
        __syncthreads();
        sm[tid] += t;
        __syncthreads();
    }
    if (gi < N_NODES) incl[gi] = sm[tid];
    if (tid == 1023) bsum[blockIdx.x] = sm[1023];
}

__global__ void k_scan2(const int* __restrict__ bsum, int* __restrict__ boff, int nb) {
    __shared__ int sm[128];
    const int tid = threadIdx.x;
    int v = (tid < nb) ? bsum[tid] : 0;
    sm[tid] = v;
    __syncthreads();
    for (int off = 1; off < 128; off <<= 1) {
        int t = (tid >= off) ? sm[tid - off] : 0;
        __syncthreads();
        sm[tid] += t;
        __syncthreads();
    }
    boff[tid] = sm[tid] - v;
}

__global__ void k_scan3(const int* __restrict__ incl, const int* __restrict__ boff,
                        int* __restrict__ rowptr) {
    int i = blockIdx.x * 256 + threadIdx.x;
    if (i < N_NODES) rowptr[i + 1] = boff[i >> 10] + incl[i];
    if (i == 0) rowptr[0] = 0;
}

__global__ void k_fill(const int* __restrict__ src, const int* __restrict__ dst,
                       const float* __restrict__ ew, const int* __restrict__ rowptr,
                       const unsigned char* __restrict__ rank,
                       unsigned* __restrict__ cw) {
    int e = blockIdx.x * 256 + threadIdx.x;
    if (e < N_EDGES) {
        int d   = dst[e];
        int pos = rowptr[d] + (int)rank[e];
        unsigned wb = (unsigned)f2bf(ew[e]) & 0x7FFFu;
        cw[pos] = ((unsigned)src[e] << 15) | wb;
    }
}

// ---------------------------------------------------------------- W packing (unchanged)
__global__ void k_wpack(const float* __restrict__ Wl, const float* __restrict__ Wr,
                        short* __restrict__ Whi, short* __restrict__ Wlo) {
    int idx = blockIdx.x * 256 + threadIdx.x;   // 32768 total
    int j  = idx & 7;
    int L  = (idx >> 3) & 63;
    int cb = (idx >> 9) & 3;
    int kb = (idx >> 11);
    int k  = kb * 16 + (L >> 5) * 8 + j;
    int n  = cb * 32 + (L & 31);
    float a = (k < 128) ? Wl[k * 128 + n] : Wr[(k - 128) * 128 + n];
    unsigned short hb = f2bf(a);
    float hf = __uint_as_float((unsigned)hb << 16);
    Whi[idx] = (short)hb;
    Wlo[idx] = (short)f2bf(a - hf);
}

// ---------------------------------------------------------------- FUSED agg + GEMM, layer 1
// One wave per block, 32 output rows. Phase 1: gather this wave's own 32 node
// rows (bf16 table) -> fp32 sums -> bf16 hi/lo into XOR-swizzled LDS (split done
// once, in the latency-slack phase). Phase 2: the same wave's 32x128 K=256 MFMA
// loop reads A-frags for kb<8 straight from LDS (zero conversion VALU), kb>=8
// from global fp32 x. NO barrier anywhere -> waves slide independently, MFMA of
// one wave overlaps gather latency of others on the CU.
// Swizzle: element (row, col) at ushort idx row*128 + ((col>>3)^(row&15))*8 + (col&7):
// write = 2 accesses/bank (free), frag ds_read_b128 = uniform 8/bank (minimal).
// Output: bf16 hi+lo (51.2 MB vs old 76.8 MB fp32+hi); hHi doubles as the
// layer-2 gather table; layer-2 operands are bit-identical to the old pipeline.
__global__ __launch_bounds__(64, 2) void k_fused1(
        const unsigned short* __restrict__ xb, const int* __restrict__ rowptr,
        const unsigned* __restrict__ cw, const float* __restrict__ Ax,
        const short* __restrict__ Whi, const short* __restrict__ Wlo,
        const float* __restrict__ bl,
        const float* __restrict__ bng, const float* __restrict__ bnb,
        const float* __restrict__ bnm, const float* __restrict__ bnv,
        unsigned short* __restrict__ outHi, unsigned short* __restrict__ outLo) {
    __shared__ unsigned short HiS[32 * 128];
    __shared__ unsigned short LoS[32 * 128];
    const int lane = threadIdx.x & 63;
    const int half = lane >> 5;
    const int cl   = lane & 31;
    const int row0 = blockIdx.x * 32;     // 3125*32 == N_NODES exactly

    unsigned short* const myLds = half ? LoS : HiS;

    // ---- phase 1: gather ----
#pragma unroll 1
    for (int nl = 0; nl < 32; ++nl) {
        const int node = row0 + nl;
        float a0 = 0.f, a1 = 0.f, a2 = 0.f, a3 = 0.f;
        {
            const int s = rowptr[node], e = rowptr[node + 1];
            for (int j0 = s; j0 < e; j0 += 8) {
                int ss[4]; float ww[4];
#pragma unroll
                for (int u = 0; u < 4; ++u) {
                    const int j  = j0 + 2 * u + half;
                    const int jc = min(j, e - 1);
                    const unsigned p = cw[jc];
                    ss[u] = (int)(p >> 15);
                    ww[u] = (j < e) ? __uint_as_float((p & 0x7FFFu) << 16) : 0.f;
                }
                uint2 g[4];
#pragma unroll
                for (int u = 0; u < 4; ++u)
                    g[u] = *(const uint2*)(xb + (size_t)ss[u] * 128 + cl * 4);
#pragma unroll
                for (int u = 0; u < 4; ++u) {
                    const float f0 = __uint_as_float(g[u].x << 16);
                    const float f1 = __uint_as_float(g[u].x & 0xFFFF0000u);
                    const float f2 = __uint_as_float(g[u].y << 16);
                    const float f3 = __uint_as_float(g[u].y & 0xFFFF0000u);
                    a0 = fmaf(ww[u], f0, a0);
                    a1 = fmaf(ww[u], f1, a1);
                    a2 = fmaf(ww[u], f2, a2);
                    a3 = fmaf(ww[u], f3, a3);
                }
            }
            a0 += __shfl_xor(a0, 32, 64);
            a1 += __shfl_xor(a1, 32, 64);
            a2 += __shfl_xor(a2, 32, 64);
            a3 += __shfl_xor(a3, 32, 64);
            const float inv = 1.f / fmaxf((float)(e - s), 1.f);
            a0 *= inv; a1 *= inv; a2 *= inv; a3 *= inv;
        }
        unsigned short v0, v1, v2, v3;
        if (half == 0) {
            v0 = f2bf(a0); v1 = f2bf(a1); v2 = f2bf(a2); v3 = f2bf(a3);
        } else {
            const unsigned short h0 = f2bf(a0), h1 = f2bf(a1),
                                 h2 = f2bf(a2), h3 = f2bf(a3);
            v0 = f2bf(a0 - bf2f(h0)); v1 = f2bf(a1 - bf2f(h1));
            v2 = f2bf(a2 - bf2f(h2)); v3 = f2bf(a3 - bf2f(h3));
        }
        uint2 wv;
        wv.x = (unsigned)v0 | ((unsigned)v1 << 16);
        wv.y = (unsigned)v2 | ((unsigned)v3 << 16);
        const int slot = (cl >> 1) ^ (nl & 15);
        *(uint2*)(myLds + nl * 128 + slot * 8 + (cl & 1) * 4) = wv;
    }

    // ---- phase 2: 32x128 GEMM, K=256, split-bf16 (3 MFMA per frag) ----
    const int rrow = cl;
    const int kq   = half;
    const int arow = row0 + rrow;         // always < N_NODES (exact tiling)
    floatx16 acc[4];
#pragma unroll
    for (int cb = 0; cb < 4; ++cb)
#pragma unroll
        for (int r = 0; r < 16; ++r) acc[cb][r] = 0.f;

#pragma unroll 2
    for (int kb = 0; kb < 8; ++kb) {      // agg half: A from LDS, pre-split
        const int slot = (2 * kb + kq) ^ (rrow & 15);
        const short8 Ah = *(const short8*)(HiS + rrow * 128 + slot * 8);
        const short8 Al = *(const short8*)(LoS + rrow * 128 + slot * 8);
#pragma unroll
        for (int cb = 0; cb < 4; ++cb) {
            const size_t wo = ((size_t)(kb * 4 + cb) * 64 + lane) * 8;
            const short8 wh = *(const short8*)(Whi + wo);
            const short8 wl = *(const short8*)(Wlo + wo);
            acc[cb] = __builtin_amdgcn_mfma_f32_32x32x16_bf16(Ah, wh, acc[cb], 0, 0, 0);
            acc[cb] = __builtin_amdgcn_mfma_f32_32x32x16_bf16(Al, wh, acc[cb], 0, 0, 0);
            acc[cb] = __builtin_amdgcn_mfma_f32_32x32x16_bf16(Ah, wl, acc[cb], 0, 0, 0);
        }
    }

    const float* Abase1 = Ax + (size_t)arow * 128 + kq * 8;
#pragma unroll 2
    for (int kb = 8; kb < 16; ++kb) {     // root half: A from global fp32 x
        const float* ap = Abase1 + (kb & 7) * 16;
        const float4 p0 = *(const float4*)(ap);
        const float4 p1 = *(const float4*)(ap + 4);
        const float av[8] = {p0.x, p0.y, p0.z, p0.w, p1.x, p1.y, p1.z, p1.w};
        short8 Ah, Al;
#pragma unroll
        for (int j = 0; j < 8; ++j) {
            const unsigned short hb = f2bf(av[j]);
            Ah[j] = (short)hb;
            Al[j] = (short)f2bf(av[j] - bf2f(hb));
        }
#pragma unroll
        for (int cb = 0; cb < 4; ++cb) {
            const size_t wo = ((size_t)(kb * 4 + cb) * 64 + lane) * 8;
            const short8 wh = *(const short8*)(Whi + wo);
            const short8 wl = *(const short8*)(Wlo + wo);
            acc[cb] = __builtin_amdgcn_mfma_f32_32x32x16_bf16(Ah, wh, acc[cb], 0, 0, 0);
            acc[cb] = __builtin_amdgcn_mfma_f32_32x32x16_bf16(Al, wh, acc[cb], 0, 0, 0);
            acc[cb] = __builtin_amdgcn_mfma_f32_32x32x16_bf16(Ah, wl, acc[cb], 0, 0, 0);
        }
    }

    // ---- epilogue: bn + relu -> bf16 hi/lo ----
#pragma unroll
    for (int cb = 0; cb < 4; ++cb) {
        const int c = cb * 32 + cl;
        const float s = bng[c] * rsqrtf(bnv[c] + 1e-5f);
        const float t = (bl[c] - bnm[c]) * s + bnb[c];
#pragma unroll
        for (int r = 0; r < 16; ++r) {
            const int row = row0 + (r & 3) + 8 * (r >> 2) + 4 * kq;
            const float v = fmaxf(fmaf(acc[cb][r], s, t), 0.f);
            const unsigned short hb = f2bf(v);
            outHi[(size_t)row * 128 + c] = hb;
            outLo[(size_t)row * 128 + c] = f2bf(v - bf2f(hb));
        }
    }
}

// ---------------------------------------------------------------- FUSED agg + GEMM + lin3, layer 2
// Same structure; root operand comes pre-split (hHi/hLo short8 loads, zero
// conversion VALU), and the epilogue folds layer-3's per-node transform:
// t4[node] = [h@w3l | h@w3r] computed from the accumulators in-register
// (per-r accumulate over cb, 5-step shfl reduce over the 32 col-lanes).
// hB (51.2 MB write + 51.2 MB read) and k_lin3 are eliminated.
__global__ __launch_bounds__(64, 2) void k_fused2(
        const unsigned short* __restrict__ hHi, const unsigned short* __restrict__ hLo,
        const int* __restrict__ rowptr, const unsigned* __restrict__ cw,
        const short* __restrict__ Whi, const short* __restrict__ Wlo,
        const float* __restrict__ bl,
        const float* __restrict__ bng, const float* __restrict__ bnb,
        const float* __restrict__ bnm, const float* __restrict__ bnv,
        const float* __restrict__ w3l, const float* __restrict__ w3r,
        float* __restrict__ t4) {
    __shared__ unsigned short HiS[32 * 128];
    __shared__ unsigned short LoS[32 * 128];
    const int lane = threadIdx.x & 63;
    const int half = lane >> 5;
    const int cl   = lane & 31;
    const int row0 = blockIdx.x * 32;

    unsigned short* const myLds = half ? LoS : HiS;

#pragma unroll 1
    for (int nl = 0; nl < 32; ++nl) {
        const int node = row0 + nl;
        float a0 = 0.f, a1 = 0.f, a2 = 0.f, a3 = 0.f;
        {
            const int s = rowptr[node], e = rowptr[node + 1];
            for (int j0 = s; j0 < e; j0 += 8) {
                int ss[4]; float ww[4];
#pragma unroll
                for (int u = 0; u < 4; ++u) {
                    const int j  = j0 + 2 * u + half;
                    const int jc = min(j, e - 1);
                    const unsigned p = cw[jc];
                    ss[u] = (int)(p >> 15);
                    ww[u] = (j < e) ? __uint_as_float((p & 0x7FFFu) << 16) : 0.f;
                }
                uint2 g[4];
#pragma unroll
                for (int u = 0; u < 4; ++u)
                    g[u] = *(const uint2*)(hHi + (size_t)ss[u] * 128 + cl * 4);
#pragma unroll
                for (int u = 0; u < 4; ++u) {
                    const float f0 = __uint_as_float(g[u].x << 16);
                    const float f1 = __uint_as_float(g[u].x & 0xFFFF0000u);
                    const float f2 = __uint_as_float(g[u].y << 16);
                    const float f3 = __uint_as_float(g[u].y & 0xFFFF0000u);
                    a0 = fmaf(ww[u], f0, a0);
                    a1 = fmaf(ww[u], f1, a1);
                    a2 = fmaf(ww[u], f2, a2);
                    a3 = fmaf(ww[u], f3, a3);
                }
            }
            a0 += __shfl_xor(a0, 32, 64);
            a1 += __shfl_xor(a1, 32, 64);
            a2 += __shfl_xor(a2, 32, 64);
            a3 += __shfl_xor(a3, 32, 64);
            const float inv = 1.f / fmaxf((float)(e - s), 1.f);
            a0 *= inv; a1 *= inv; a2 *= inv; a3 *= inv;
        }
        unsigned short v0, v1, v2, v3;
        if (half == 0) {
            v0 = f2bf(a0); v1 = f2bf(a1); v2 = f2bf(a2); v3 = f2bf(a3);
        } else {
            const unsigned short h0 = f2bf(a0), h1 = f2bf(a1),
                                 h2 = f2bf(a2), h3 = f2bf(a3);
            v0 = f2bf(a0 - bf2f(h0)); v1 = f2bf(a1 - bf2f(h1));
            v2 = f2bf(a2 - bf2f(h2)); v3 = f2bf(a3 - bf2f(h3));
        }
        uint2 wv;
        wv.x = (unsigned)v0 | ((unsigned)v1 << 16);
        wv.y = (unsigned)v2 | ((unsigned)v3 << 16);
        const int slot = (cl >> 1) ^ (nl & 15);
        *(uint2*)(myLds + nl * 128 + slot * 8 + (cl & 1) * 4) = wv;
    }

    const int rrow = cl;
    const int kq   = half;
    const int arow = row0 + rrow;
    floatx16 acc[4];
#pragma unroll
    for (int cb = 0; cb < 4; ++cb)
#pragma unroll
        for (int r = 0; r < 16; ++r) acc[cb][r] = 0.f;

#pragma unroll 2
    for (int kb = 0; kb < 8; ++kb) {      // agg half from LDS
        const int slot = (2 * kb + kq) ^ (rrow & 15);
        const short8 Ah = *(const short8*)(HiS + rrow * 128 + slot * 8);
        const short8 Al = *(const short8*)(LoS + rrow * 128 + slot * 8);
#pragma unroll
        for (int cb = 0; cb < 4; ++cb) {
            const size_t wo = ((size_t)(kb * 4 + cb) * 64 + lane) * 8;
            const short8 wh = *(const short8*)(Whi + wo);
            const short8 wl = *(const short8*)(Wlo + wo);
            acc[cb] = __builtin_amdgcn_mfma_f32_32x32x16_bf16(Ah, wh, acc[cb], 0, 0, 0);
            acc[cb] = __builtin_amdgcn_mfma_f32_32x32x16_bf16(Al, wh, acc[cb], 0, 0, 0);
            acc[cb] = __builtin_amdgcn_mfma_f32_32x32x16_bf16(Ah, wl, acc[cb], 0, 0, 0);
        }
    }

#pragma unroll 2
    for (int kb = 8; kb < 16; ++kb) {     // root half: pre-split bf16 hi/lo, direct frag loads
        const size_t axo = (size_t)arow * 128 + (kb & 7) * 16 + kq * 8;
        const short8 Ah = *(const short8*)(hHi + axo);
        const short8 Al = *(const short8*)(hLo + axo);
#pragma unroll
        for (int cb = 0; cb < 4; ++cb) {
            const size_t wo = ((size_t)(kb * 4 + cb) * 64 + lane) * 8;
            const short8 wh = *(const short8*)(Whi + wo);
            const short8 wl = *(const short8*)(Wlo + wo);
            acc[cb] = __builtin_amdgcn_mfma_f32_32x32x16_bf16(Ah, wh, acc[cb], 0, 0, 0);
            acc[cb] = __builtin_amdgcn_mfma_f32_32x32x16_bf16(Al, wh, acc[cb], 0, 0, 0);
            acc[cb] = __builtin_amdgcn_mfma_f32_32x32x16_bf16(Ah, wl, acc[cb], 0, 0, 0);
        }
    }

    // ---- epilogue: bn+relu, fused layer-3 transform -> t4 ----
    float q0[16], q1[16], q2[16], q3[16];
#pragma unroll
    for (int r = 0; r < 16; ++r) { q0[r] = 0.f; q1[r] = 0.f; q2[r] = 0.f; q3[r] = 0.f; }
#pragma unroll
    for (int cb = 0; cb < 4; ++cb) {
        const int c = cb * 32 + cl;
        const float s = bng[c] * rsqrtf(bnv[c] + 1e-5f);
        const float t = (bl[c] - bnm[c]) * s + bnb[c];
        const float2 wL = *(const float2*)(w3l + c * 2);
        const float2 wR = *(const float2*)(w3r + c * 2);
#pragma unroll
        for (int r = 0; r < 16; ++r) {
            const float v = fmaxf(fmaf(acc[cb][r], s, t), 0.f);
            q0[r] = fmaf(v, wL.x, q0[r]);
            q1[r] = fmaf(v, wL.y, q1[r]);
            q2[r] = fmaf(v, wR.x, q2[r]);
            q3[r] = fmaf(v, wR.y, q3[r]);
        }
    }
#pragma unroll
    for (int m = 1; m <= 16; m <<= 1) {
#pragma unroll
        for (int r = 0; r < 16; ++r) {
            q0[r] += __shfl_xor(q0[r], m, 64);
            q1[r] += __shfl_xor(q1[r], m, 64);
            q2[r] += __shfl_xor(q2[r], m, 64);
            q3[r] += __shfl_xor(q3[r], m, 64);
        }
    }
    float z0 = q0[0], z1 = q1[0], z2 = q2[0], z3 = q3[0];
#pragma unroll
    for (int r = 1; r < 16; ++r) {
        if (cl == r) { z0 = q0[r]; z1 = q1[r]; z2 = q2[r]; z3 = q3[r]; }
    }
    if (cl < 16) {
        const int row = row0 + (cl & 3) + 8 * (cl >> 2) + 4 * kq;
        float4 o; o.x = z0; o.y = z1; o.z = z2; o.w = z3;
        *(float4*)(t4 + (size_t)row * 4) = o;
    }
}

// ---------------------------------------------------------------- final edge aggregate (unchanged)
__global__ void k_out(const float* __restrict__ t4, const int* __restrict__ rowptr,
                      const unsigned* __restrict__ cw,
                      const float* __restrict__ b3, float* __restrict__ out) {
    const int lane = threadIdx.x & 63;
    const int node = blockIdx.x * (blockDim.x >> 6) + (threadIdx.x >> 6);
    if (node >= N_NODES) return;
    const int s = rowptr[node], e = rowptr[node + 1];
    float a0 = 0.f, a1 = 0.f;
    for (int j = s + lane; j < e; j += 64) {
        const unsigned p = cw[j];
        const int   sr = (int)(p >> 15);
        const float w  = __uint_as_float((p & 0x7FFFu) << 16);
        float2 t = *(const float2*)(t4 + (size_t)sr * 4);
        a0 += w * t.x; a1 += w * t.y;
    }
#pragma unroll
    for (int m = 1; m < 64; m <<= 1) {
        a0 += __shfl_xor(a0, m, 64);
        a1 += __shfl_xor(a1, m, 64);
    }
    if (lane == 0) {
        float inv = 1.f / fmaxf((float)(e - s), 1.f);
        float2 o;
        o.x = a0 * inv + b3[0] + t4[(size_t)node * 4 + 2];
        o.y = a1 * inv + b3[1] + t4[(size_t)node * 4 + 3];
        *(float2*)(out + (size_t)node * 2) = o;
    }
}

// ---------------------------------------------------------------- launch
extern "C" void kernel_launch(void* const* d_in, const int* in_sizes, int n_in,
                              void* d_out, int out_size, void* d_ws, size_t ws_size,
                              hipStream_t stream) {
    const float* x    = (const float*)d_in[0];
    const float* ea   = (const float*)d_in[1];
    const int*   ei   = (const int*)d_in[2];
    const float* ew1w = (const float*)d_in[3];
    const float* ew1b = (const float*)d_in[4];
    const float* ew2w = (const float*)d_in[5];
    const float* ew2b = (const float*)d_in[6];
    const float* w1l  = (const float*)d_in[7];
    const float* b1l  = (const float*)d_in[8];
    const float* w1r  = (const float*)d_in[9];
    const float* w2l  = (const float*)d_in[10];
    const float* b2l  = (const float*)d_in[11];
    const float* w2r  = (const float*)d_in[12];
    const float* w3l  = (const float*)d_in[13];
    const float* b3l  = (const float*)d_in[14];
    const float* w3r  = (const float*)d_in[15];
    const float* bn1g = (const float*)d_in[16];
    const float* bn1b = (const float*)d_in[17];
    const float* bn1m = (const float*)d_in[18];
    const float* bn1v = (const float*)d_in[19];
    const float* bn2g = (const float*)d_in[20];
    const float* bn2b = (const float*)d_in[21];
    const float* bn2m = (const float*)d_in[22];
    const float* bn2v = (const float*)d_in[23];

    const int* src = ei;
    const int* dst = ei + N_EDGES;
    float* out = (float*)d_out;

    size_t off = 0;
    auto carve = [&](size_t bytes) -> void* {
        void* p = (char*)d_ws + off;
        off += (bytes + 255) & ~(size_t)255;
        return p;
    };
    float* ew     = (float*)carve((size_t)N_EDGES * 4);
    unsigned* cw  = (unsigned*)carve((size_t)N_EDGES * 4);
    unsigned char* rank = (unsigned char*)carve((size_t)N_EDGES);
    int*   rowptr = (int*)carve((size_t)(N_NODES + 1) * 4);
    int*   deg    = (int*)carve((size_t)N_NODES * 4);
    int*   bsum   = (int*)carve(128 * 4);
    int*   boff   = (int*)carve(128 * 4);
    int*   incl   = (int*)carve((size_t)N_NODES * 4);
    float* t4     = (float*)carve((size_t)N_NODES * 4 * 4);
    short* W1hi   = (short*)carve(32768 * 2);
    short* W1lo   = (short*)carve(32768 * 2);
    short* W2hi   = (short*)carve(32768 * 2);
    short* W2lo   = (short*)carve(32768 * 2);
    unsigned short* xb  = (unsigned short*)carve((size_t)N_NODES * 128 * 2);
    unsigned short* hHi = (unsigned short*)carve((size_t)N_NODES * 128 * 2);
    unsigned short* hLo = (unsigned short*)carve((size_t)N_NODES * 128 * 2);
    (void)ws_size; (void)n_in; (void)in_sizes; (void)out_size;

    hipMemsetAsync(deg, 0, (size_t)N_NODES * 4, stream);

    const int EB = (N_EDGES + 255) / 256;        // 6250
    const int NB_SCAN = (N_NODES + 1023) / 1024; // 98
    const int NWB = (N_NODES + 3) / 4;           // 25000
    const int CB = (N_NODES * 128 / 4 + 255) / 256;  // 12500
    const int FB = N_NODES / 32;                 // 3125 (exact)

    k_cast_deg<<<CB, 256, 0, stream>>>(x, xb, dst, deg, rank);
    k_edge_mlp<<<2048, 256, 0, stream>>>(ea, ew1w, ew1b, ew2w, ew2b, ew);
    k_wpack<<<128, 256, 0, stream>>>(w1l, w1r, W1hi, W1lo);
    k_wpack<<<128, 256, 0, stream>>>(w2l, w2r, W2hi, W2lo);
    k_scan1<<<NB_SCAN, 1024, 0, stream>>>(deg, incl, bsum);
    k_scan2<<<1, 128, 0, stream>>>(bsum, boff, NB_SCAN);
    k_scan3<<<(N_NODES + 255) / 256, 256, 0, stream>>>(incl, boff, rowptr);
    k_fill<<<EB, 256, 0, stream>>>(src, dst, ew, rowptr, rank, cw);

    // layer 1 (fused gather + GEMM) -> bf16 hi/lo
    k_fused1<<<FB, 64, 0, stream>>>(xb, rowptr, cw, x, W1hi, W1lo, b1l,
                                    bn1g, bn1b, bn1m, bn1v, hHi, hLo);
    // layer 2 (fused gather + GEMM + layer-3 transform) -> t4
    k_fused2<<<FB, 64, 0, stream>>>(hHi, hLo, rowptr, cw, W2hi, W2lo, b2l,
                                    bn2g, bn2b, bn2m, bn2v, w3l, w3r, t4);
    // layer 3 edge aggregate
    k_out<<<NWB, 256, 0, stream>>>(t4, rowptr, cw, b3l, out);
}

// Round 2
// 594.276 us; speedup vs baseline: 1.1099x; 1.1099x over previous
//
#include <hip/hip_runtime.h>
#include <math.h>

#define N_NODES 100000
#define N_EDGES 1600000
#define F_INF   128
#define HIDF    128

typedef __attribute__((ext_vector_type(8)))  short short8;
typedef __attribute__((ext_vector_type(16))) float floatx16;

__device__ __forceinline__ unsigned short f2bf(float f) {
    unsigned u = __float_as_uint(f);
    return (unsigned short)((u + 0x7FFFu + ((u >> 16) & 1u)) >> 16);
}
__device__ __forceinline__ float bf2f(unsigned short h) {
    return __uint_as_float((unsigned)h << 16);
}

// ---------------------------------------------------------------- edge MLP
// MFMA formulation: one wave = 32 edges per iteration (proven, unchanged).
__global__ __launch_bounds__(256) void k_edge_mlp(
        const float* __restrict__ ea,
        const float* __restrict__ w1, const float* __restrict__ b1,
        const float* __restrict__ w2, const float* __restrict__ b2,
        float* __restrict__ ew) {
    const int lane = threadIdx.x & 63;
    const int cl   = lane & 31;
    const int half = lane >> 5;
    const int wid  = blockIdx.x * (blockDim.x >> 6) + (threadIdx.x >> 6);
    const int nw   = gridDim.x * (blockDim.x >> 6);

    short8 bw[4];
    float  w2c[4];
#pragma unroll
    for (int cb = 0; cb < 4; ++cb) {
        const int n = cb * 32 + cl;
        short8 b;
        if (half == 0) {
#pragma unroll
            for (int j = 0; j < 8; ++j) b[j] = (short)f2bf(w1[j * 128 + n]);
        } else {
            b[0] = (short)f2bf(b1[n]);
#pragma unroll
            for (int j = 1; j < 8; ++j) b[j] = 0;
        }
        bw[cb] = b;
        w2c[cb] = w2[n];
    }
    short8 Abias;
    Abias[0] = (short)0x3F80;
#pragma unroll
    for (int j = 1; j < 8; ++j) Abias[j] = 0;

    floatx16 czero;
#pragma unroll
    for (int r = 0; r < 16; ++r) czero[r] = 0.f;

    const float bias2 = b2[0];

    for (int e0 = wid * 32; e0 < N_EDGES; e0 += nw * 32) {
        short8 Ah;
        if (half == 0) {
            const float4 a0 = *(const float4*)(ea + (size_t)(e0 + cl) * 8);
            const float4 a1 = *(const float4*)(ea + (size_t)(e0 + cl) * 8 + 4);
            Ah[0] = (short)f2bf(a0.x); Ah[1] = (short)f2bf(a0.y);
            Ah[2] = (short)f2bf(a0.z); Ah[3] = (short)f2bf(a0.w);
            Ah[4] = (short)f2bf(a1.x); Ah[5] = (short)f2bf(a1.y);
            Ah[6] = (short)f2bf(a1.z); Ah[7] = (short)f2bf(a1.w);
        } else {
            Ah = Abias;
        }

        float z[16];
#pragma unroll
        for (int r = 0; r < 16; ++r) z[r] = 0.f;

#pragma unroll
        for (int cb = 0; cb < 4; ++cb) {
            floatx16 acc = __builtin_amdgcn_mfma_f32_32x32x16_bf16(Ah, bw[cb], czero, 0, 0, 0);
#pragma unroll
            for (int r = 0; r < 16; ++r)
                z[r] = fmaf(fmaxf(acc[r], 0.f), w2c[cb], z[r]);
        }

#pragma unroll
        for (int m = 1; m <= 16; m <<= 1) {
#pragma unroll
            for (int r = 0; r < 16; ++r) z[r] += __shfl_xor(z[r], m, 64);
        }

        float zz = z[0];
#pragma unroll
        for (int r = 1; r < 16; ++r) zz = (cl == r) ? z[r] : zz;
        if (cl < 16) {
            const int row = (cl & 3) + 8 * (cl >> 2) + 4 * half;
            ew[e0 + row] = 1.f / (1.f + __expf(-(zz + bias2)));
        }
    }
}

// ---------------------------------------------------------------- cast + degree (MERGED)
// Atomic histogram (memory-side RMW wall, ~51 MB write-through) hidden under
// the independent streaming x -> bf16 hi/lo cast. The kernel is atomic-bound
// with idle BW, so the extra xbLo store (25.6 MB) is ~free; it deletes the
// fp32->hi/lo split VALU from gemm1's root-operand path.
__global__ void k_cast_deg(const float* __restrict__ x,
                           unsigned short* __restrict__ xbHi,
                           unsigned short* __restrict__ xbLo,
                           const int* __restrict__ dst, int* __restrict__ deg,
                           unsigned char* __restrict__ rank) {
    const int gid = blockIdx.x * 256 + threadIdx.x;     // 0 .. 3.2M-1
    const int i = gid * 4;                               // N*128 elems exactly
    const float4 v = *(const float4*)(x + i);
    ushort4 h, l;
    h.x = f2bf(v.x); l.x = f2bf(v.x - bf2f(h.x));
    h.y = f2bf(v.y); l.y = f2bf(v.y - bf2f(h.y));
    h.z = f2bf(v.z); l.z = f2bf(v.z - bf2f(h.z));
    h.w = f2bf(v.w); l.w = f2bf(v.w - bf2f(h.w));
    *(ushort4*)(xbHi + i) = h;
    *(ushort4*)(xbLo + i) = l;
    if ((gid & 1) == 0) {
        const int e = gid >> 1;                          // covers all 1.6M edges exactly
        rank[e] = (unsigned char)atomicAdd(&deg[dst[e]], 1);
    }
}

// ---------------------------------------------------------------- CSR build (unchanged)
__global__ void k_scan1(const int* __restrict__ deg, int* __restrict__ incl,
                        int* __restrict__ bsum) {
    __shared__ int sm[1024];
    const int tid = threadIdx.x;
    const int gi  = blockIdx.x * 1024 + tid;
    int v = (gi < N_NODES) ? deg[gi] : 0;
    sm[tid] = v;
    __syncthreads();
    for (int off = 1; off < 1024; off <<= 1) {
        int t = (tid >= off) ? sm[tid - off] : 0;
        __syncthreads();
        sm[tid] += t;
        __syncthreads();
    }
    if (gi < N_NODES) incl[gi] = sm[tid];
    if (tid == 1023) bsum[blockIdx.x] = sm[1023];
}

__global__ void k_scan2(const int* __restrict__ bsum, int* __restrict__ boff, int nb) {
    __shared__ int sm[128];
    const int tid = threadIdx.x;
    int v = (tid < nb) ? bsum[tid] : 0;
    sm[tid] = v;
    __syncthreads();
    for (int off = 1; off < 128; off <<= 1) {
        int t = (tid >= off) ? sm[tid - off] : 0;
        __syncthreads();
        sm[tid] += t;
        __syncthreads();
    }
    boff[tid] = sm[tid] - v;
}

__global__ void k_scan3(const int* __restrict__ incl, const int* __restrict__ boff,
                        int* __restrict__ rowptr) {
    int i = blockIdx.x * 256 + threadIdx.x;
    if (i < N_NODES) rowptr[i + 1] = boff[i >> 10] + incl[i];
    if (i == 0) rowptr[0] = 0;
}

__global__ void k_fill(const int* __restrict__ src, const int* __restrict__ dst,
                       const float* __restrict__ ew, const int* __restrict__ rowptr,
                       const unsigned char* __restrict__ rank,
                       unsigned* __restrict__ cw) {
    int e = blockIdx.x * 256 + threadIdx.x;
    if (e < N_EDGES) {
        int d   = dst[e];
        int pos = rowptr[d] + (int)rank[e];
        unsigned wb = (unsigned)f2bf(ew[e]) & 0x7FFFu;
        cw[pos] = ((unsigned)src[e] << 15) | wb;
    }
}

// ---------------------------------------------------------------- W packing (unchanged)
__global__ void k_wpack(const float* __restrict__ Wl, const float* __restrict__ Wr,
                        short* __restrict__ Whi, short* __restrict__ Wlo) {
    int idx = blockIdx.x * 256 + threadIdx.x;   // 32768 total
    int j  = idx & 7;
    int L  = (idx >> 3) & 63;
    int cb = (idx >> 9) & 3;
    int kb = (idx >> 11);
    int k  = kb * 16 + (L >> 5) * 8 + j;
    int n  = cb * 32 + (L & 31);
    float a = (k < 128) ? Wl[k * 128 + n] : Wr[(k - 128) * 128 + n];
    unsigned short hb = f2bf(a);
    float hf = __uint_as_float((unsigned)hb << 16);
    Whi[idx] = (short)hb;
    Wlo[idx] = (short)f2bf(a - hf);
}

// ---------------------------------------------------------------- aggregation (bf16 gather)
// REVERTED to round-0 structure (wave per node, 25000x4-wave blocks, high
// occupancy — the round-1 per-wave fusion died at 16% occupancy). Only change:
// epilogue writes bf16 hi/lo (same byte count as fp32) so the GEMM consumes
// pre-split fragments with zero conversion VALU.
__global__ __launch_bounds__(256) void k_agg16(
        const unsigned short* __restrict__ xb, const int* __restrict__ rowptr,
        const unsigned* __restrict__ cw,
        unsigned short* __restrict__ aggHi, unsigned short* __restrict__ aggLo) {
    const int lane = threadIdx.x & 63;
    const int half = lane >> 5;          // which edge of the pair
    const int cl   = lane & 31;          // cols cl*4 .. cl*4+3
    const int node = blockIdx.x * (blockDim.x >> 6) + (threadIdx.x >> 6);
    if (node >= N_NODES) return;
    const int s = rowptr[node], e = rowptr[node + 1];
    float a0 = 0.f, a1 = 0.f, a2 = 0.f, a3 = 0.f;

    for (int j0 = s; j0 < e; j0 += 8) {
        int ss[4]; float ww[4];
#pragma unroll
        for (int u = 0; u < 4; ++u) {
            const int j  = j0 + 2 * u + half;
            const int jc = min(j, e - 1);
            const unsigned p = cw[jc];
            ss[u] = (int)(p >> 15);
            ww[u] = (j < e) ? __uint_as_float((p & 0x7FFFu) << 16) : 0.f;
        }
        uint2 g[4];
#pragma unroll
        for (int u = 0; u < 4; ++u)
            g[u] = *(const uint2*)(xb + (size_t)ss[u] * 128 + cl * 4);
#pragma unroll
        for (int u = 0; u < 4; ++u) {
            const float f0 = __uint_as_float(g[u].x << 16);
            const float f1 = __uint_as_float(g[u].x & 0xFFFF0000u);
            const float f2 = __uint_as_float(g[u].y << 16);
            const float f3 = __uint_as_float(g[u].y & 0xFFFF0000u);
            a0 = fmaf(ww[u], f0, a0);
            a1 = fmaf(ww[u], f1, a1);
            a2 = fmaf(ww[u], f2, a2);
            a3 = fmaf(ww[u], f3, a3);
        }
    }
    a0 += __shfl_xor(a0, 32, 64);
    a1 += __shfl_xor(a1, 32, 64);
    a2 += __shfl_xor(a2, 32, 64);
    a3 += __shfl_xor(a3, 32, 64);
    if (half == 0) {
        const float inv = 1.f / fmaxf((float)(e - s), 1.f);
        a0 *= inv; a1 *= inv; a2 *= inv; a3 *= inv;
        ushort4 h, l;
        h.x = f2bf(a0); l.x = f2bf(a0 - bf2f(h.x));
        h.y = f2bf(a1); l.y = f2bf(a1 - bf2f(h.y));
        h.z = f2bf(a2); l.z = f2bf(a2 - bf2f(h.z));
        h.w = f2bf(a3); l.w = f2bf(a3 - bf2f(h.w));
        *(ushort4*)(aggHi + (size_t)node * 128 + cl * 4) = h;
        *(ushort4*)(aggLo + (size_t)node * 128 + cl * 4) = l;
    }
}

// ---------------------------------------------------------------- MFMA GEMM, layer 1
// All A operands pre-split bf16 hi/lo (direct short8 frag loads, zero
// conversion VALU). K=256 (agg ++ root), 3 MFMA per frag (Ah*Wh, Al*Wh, Ah*Wl).
// Epilogue: bn + relu -> bf16 hi/lo (51.2 MB, was 76.8 fp32+bf16).
__global__ __launch_bounds__(256) void k_gemm1(
    const unsigned short* __restrict__ AaggHi, const unsigned short* __restrict__ AaggLo,
    const unsigned short* __restrict__ AxHi, const unsigned short* __restrict__ AxLo,
    const short* __restrict__ Whi, const short* __restrict__ Wlo,
    const float* __restrict__ bl,
    const float* __restrict__ bng, const float* __restrict__ bnb,
    const float* __restrict__ bnm, const float* __restrict__ bnv,
    unsigned short* __restrict__ outHi, unsigned short* __restrict__ outLo) {
    const int tid  = threadIdx.x;
    const int lane = tid & 63;
    const int w    = tid >> 6;
    const int row0 = blockIdx.x * 128 + w * 32;
    const int rrow = lane & 31;
    const int kq   = lane >> 5;
    const int arow = min(row0 + rrow, N_NODES - 1);

    floatx16 acc[4];
#pragma unroll
    for (int cb = 0; cb < 4; ++cb)
#pragma unroll
        for (int r = 0; r < 16; ++r) acc[cb][r] = 0.f;

    const size_t abase = (size_t)arow * 128 + kq * 8;

#pragma unroll 2
    for (int kb = 0; kb < 16; ++kb) {
        const size_t ao = abase + (kb & 7) * 16;
        const short8 Ah = *(const short8*)(((kb < 8) ? AaggHi : AxHi) + ao);
        const short8 Al = *(const short8*)(((kb < 8) ? AaggLo : AxLo) + ao);
#pragma unroll
        for (int cb = 0; cb < 4; ++cb) {
            const size_t wo = ((size_t)(kb * 4 + cb) * 64 + lane) * 8;
            const short8 wh = *(const short8*)(Whi + wo);
            const short8 wl = *(const short8*)(Wlo + wo);
            acc[cb] = __builtin_amdgcn_mfma_f32_32x32x16_bf16(Ah, wh, acc[cb], 0, 0, 0);
            acc[cb] = __builtin_amdgcn_mfma_f32_32x32x16_bf16(Al, wh, acc[cb], 0, 0, 0);
            acc[cb] = __builtin_amdgcn_mfma_f32_32x32x16_bf16(Ah, wl, acc[cb], 0, 0, 0);
        }
    }

#pragma unroll
    for (int cb = 0; cb < 4; ++cb) {
        const int c = cb * 32 + (lane & 31);
        const float s = bng[c] * rsqrtf(bnv[c] + 1e-5f);
        const float t = (bl[c] - bnm[c]) * s + bnb[c];
#pragma unroll
        for (int r = 0; r < 16; ++r) {
            const int row = row0 + (r & 3) + 8 * (r >> 2) + 4 * kq;
            if (row < N_NODES) {
                const float v = fmaxf(fmaf(acc[cb][r], s, t), 0.f);
                const unsigned short hb = f2bf(v);
                outHi[(size_t)row * 128 + c] = hb;
                outLo[(size_t)row * 128 + c] = f2bf(v - bf2f(hb));
            }
        }
    }
}

// ---------------------------------------------------------------- MFMA GEMM, layer 2 (+ fused lin3)
// Same GEMM body; epilogue folds layer-3's per-node transform:
// t4[node] = [h@w3l | h@w3r] from the accumulators in-register (per-r
// accumulate over cb, 5-step shfl reduce over 32 col-lanes). This epilogue
// passed verification in round 1. hB (51.2 MB write + read) + k_lin3 deleted.
__global__ __launch_bounds__(256) void k_gemm2(
    const unsigned short* __restrict__ AaggHi, const unsigned short* __restrict__ AaggLo,
    const unsigned short* __restrict__ AxHi, const unsigned short* __restrict__ AxLo,
    const short* __restrict__ Whi, const short* __restrict__ Wlo,
    const float* __restrict__ bl,
    const float* __restrict__ bng, const float* __restrict__ bnb,
    const float* __restrict__ bnm, const float* __restrict__ bnv,
    const float* __restrict__ w3l, const float* __restrict__ w3r,
    float* __restrict__ t4) {
    const int tid  = threadIdx.x;
    const int lane = tid & 63;
    const int w    = tid >> 6;
    const int row0 = blockIdx.x * 128 + w * 32;
    const int rrow = lane & 31;
    const int kq   = lane >> 5;
    const int arow = min(row0 + rrow, N_NODES - 1);
    const int cl   = lane & 31;

    floatx16 acc[4];
#pragma unroll
    for (int cb = 0; cb < 4; ++cb)
#pragma unroll
        for (int r = 0; r < 16; ++r) acc[cb][r] = 0.f;

    const size_t abase = (size_t)arow * 128 + kq * 8;

#pragma unroll 2
    for (int kb = 0; kb < 16; ++kb) {
        const size_t ao = abase + (kb & 7) * 16;
        const short8 Ah = *(const short8*)(((kb < 8) ? AaggHi : AxHi) + ao);
        const short8 Al = *(const short8*)(((kb < 8) ? AaggLo : AxLo) + ao);
#pragma unroll
        for (int cb = 0; cb < 4; ++cb) {
            const size_t wo = ((size_t)(kb * 4 + cb) * 64 + lane) * 8;
            const short8 wh = *(const short8*)(Whi + wo);
            const short8 wl = *(const short8*)(Wlo + wo);
            acc[cb] = __builtin_amdgcn_mfma_f32_32x32x16_bf16(Ah, wh, acc[cb], 0, 0, 0);
            acc[cb] = __builtin_amdgcn_mfma_f32_32x32x16_bf16(Al, wh, acc[cb], 0, 0, 0);
            acc[cb] = __builtin_amdgcn_mfma_f32_32x32x16_bf16(Ah, wl, acc[cb], 0, 0, 0);
        }
    }

    float q0[16], q1[16], q2[16], q3[16];
#pragma unroll
    for (int r = 0; r < 16; ++r) { q0[r] = 0.f; q1[r] = 0.f; q2[r] = 0.f; q3[r] = 0.f; }
#pragma unroll
    for (int cb = 0; cb < 4; ++cb) {
        const int c = cb * 32 + cl;
        const float s = bng[c] * rsqrtf(bnv[c] + 1e-5f);
        const float t = (bl[c] - bnm[c]) * s + bnb[c];
        const float2 wL = *(const float2*)(w3l + c * 2);
        const float2 wR = *(const float2*)(w3r + c * 2);
#pragma unroll
        for (int r = 0; r < 16; ++r) {
            const float v = fmaxf(fmaf(acc[cb][r], s, t), 0.f);
            q0[r] = fmaf(v, wL.x, q0[r]);
            q1[r] = fmaf(v, wL.y, q1[r]);
            q2[r] = fmaf(v, wR.x, q2[r]);
            q3[r] = fmaf(v, wR.y, q3[r]);
        }
    }
#pragma unroll
    for (int m = 1; m <= 16; m <<= 1) {
#pragma unroll
        for (int r = 0; r < 16; ++r) {
            q0[r] += __shfl_xor(q0[r], m, 64);
            q1[r] += __shfl_xor(q1[r], m, 64);
            q2[r] += __shfl_xor(q2[r], m, 64);
            q3[r] += __shfl_xor(q3[r], m, 64);
        }
    }
    float z0 = q0[0], z1 = q1[0], z2 = q2[0], z3 = q3[0];
#pragma unroll
    for (int r = 1; r < 16; ++r) {
        if (cl == r) { z0 = q0[r]; z1 = q1[r]; z2 = q2[r]; z3 = q3[r]; }
    }
    if (cl < 16) {
        const int row = row0 + (cl & 3) + 8 * (cl >> 2) + 4 * kq;
        if (row < N_NODES) {
            float4 o; o.x = z0; o.y = z1; o.z = z2; o.w = z3;
            *(float4*)(t4 + (size_t)row * 4) = o;
        }
    }
}

// ---------------------------------------------------------------- final edge aggregate (unchanged)
__global__ void k_out(const float* __restrict__ t4, const int* __restrict__ rowptr,
                      const unsigned* __restrict__ cw,
                      const float* __restrict__ b3, float* __restrict__ out) {
    const int lane = threadIdx.x & 63;
    const int node = blockIdx.x * (blockDim.x >> 6) + (threadIdx.x >> 6);
    if (node >= N_NODES) return;
    const int s = rowptr[node], e = rowptr[node + 1];
    float a0 = 0.f, a1 = 0.f;
    for (int j = s + lane; j < e; j += 64) {
        const unsigned p = cw[j];
        const int   sr = (int)(p >> 15);
        const float w  = __uint_as_float((p & 0x7FFFu) << 16);
        float2 t = *(const float2*)(t4 + (size_t)sr * 4);
        a0 += w * t.x; a1 += w * t.y;
    }
#pragma unroll
    for (int m = 1; m < 64; m <<= 1) {
        a0 += __shfl_xor(a0, m, 64);
        a1 += __shfl_xor(a1, m, 64);
    }
    if (lane == 0) {
        float inv = 1.f / fmaxf((float)(e - s), 1.f);
        float2 o;
        o.x = a0 * inv + b3[0] + t4[(size_t)node * 4 + 2];
        o.y = a1 * inv + b3[1] + t4[(size_t)node * 4 + 3];
        *(float2*)(out + (size_t)node * 2) = o;
    }
}

// ---------------------------------------------------------------- launch
extern "C" void kernel_launch(void* const* d_in, const int* in_sizes, int n_in,
                              void* d_out, int out_size, void* d_ws, size_t ws_size,
                              hipStream_t stream) {
    const float* x    = (const float*)d_in[0];
    const float* ea   = (const float*)d_in[1];
    const int*   ei   = (const int*)d_in[2];
    const float* ew1w = (const float*)d_in[3];
    const float* ew1b = (const float*)d_in[4];
    const float* ew2w = (const float*)d_in[5];
    const float* ew2b = (const float*)d_in[6];
    const float* w1l  = (const float*)d_in[7];
    const float* b1l  = (const float*)d_in[8];
    const float* w1r  = (const float*)d_in[9];
    const float* w2l  = (const float*)d_in[10];
    const float* b2l  = (const float*)d_in[11];
    const float* w2r  = (const float*)d_in[12];
    const float* w3l  = (const float*)d_in[13];
    const float* b3l  = (const float*)d_in[14];
    const float* w3r  = (const float*)d_in[15];
    const float* bn1g = (const float*)d_in[16];
    const float* bn1b = (const float*)d_in[17];
    const float* bn1m = (const float*)d_in[18];
    const float* bn1v = (const float*)d_in[19];
    const float* bn2g = (const float*)d_in[20];
    const float* bn2b = (const float*)d_in[21];
    const float* bn2m = (const float*)d_in[22];
    const float* bn2v = (const float*)d_in[23];

    const int* src = ei;
    const int* dst = ei + N_EDGES;
    float* out = (float*)d_out;

    size_t off = 0;
    auto carve = [&](size_t bytes) -> void* {
        void* p = (char*)d_ws + off;
        off += (bytes + 255) & ~(size_t)255;
        return p;
    };
    float* ew     = (float*)carve((size_t)N_EDGES * 4);
    unsigned* cw  = (unsigned*)carve((size_t)N_EDGES * 4);
    unsigned char* rank = (unsigned char*)carve((size_t)N_EDGES);
    int*   rowptr = (int*)carve((size_t)(N_NODES + 1) * 4);
    int*   deg    = (int*)carve((size_t)N_NODES * 4);
    int*   bsum   = (int*)carve(128 * 4);
    int*   boff   = (int*)carve(128 * 4);
    int*   incl   = (int*)carve((size_t)N_NODES * 4);
    float* t4     = (float*)carve((size_t)N_NODES * 4 * 4);
    short* W1hi   = (short*)carve(32768 * 2);
    short* W1lo   = (short*)carve(32768 * 2);
    short* W2hi   = (short*)carve(32768 * 2);
    short* W2lo   = (short*)carve(32768 * 2);
    unsigned short* xbHi  = (unsigned short*)carve((size_t)N_NODES * 128 * 2);
    unsigned short* xbLo  = (unsigned short*)carve((size_t)N_NODES * 128 * 2);
    unsigned short* aggHi = (unsigned short*)carve((size_t)N_NODES * 128 * 2);
    unsigned short* aggLo = (unsigned short*)carve((size_t)N_NODES * 128 * 2);
    unsigned short* hHi   = (unsigned short*)carve((size_t)N_NODES * 128 * 2);
    unsigned short* hLo   = (unsigned short*)carve((size_t)N_NODES * 128 * 2);
    (void)ws_size; (void)n_in; (void)in_sizes; (void)out_size;

    hipMemsetAsync(deg, 0, (size_t)N_NODES * 4, stream);

    const int EB = (N_EDGES + 255) / 256;        // 6250
    const int NB_SCAN = (N_NODES + 1023) / 1024; // 98
    const int NWB = (N_NODES + 3) / 4;           // 25000
    const int GB = (N_NODES + 127) / 128;        // 782
    const int CB = (N_NODES * 128 / 4 + 255) / 256;  // 12500

    k_cast_deg<<<CB, 256, 0, stream>>>(x, xbHi, xbLo, dst, deg, rank);
    k_edge_mlp<<<2048, 256, 0, stream>>>(ea, ew1w, ew1b, ew2w, ew2b, ew);
    k_wpack<<<128, 256, 0, stream>>>(w1l, w1r, W1hi, W1lo);
    k_wpack<<<128, 256, 0, stream>>>(w2l, w2r, W2hi, W2lo);
    k_scan1<<<NB_SCAN, 1024, 0, stream>>>(deg, incl, bsum);
    k_scan2<<<1, 128, 0, stream>>>(bsum, boff, NB_SCAN);
    k_scan3<<<(N_NODES + 255) / 256, 256, 0, stream>>>(incl, boff, rowptr);
    k_fill<<<EB, 256, 0, stream>>>(src, dst, ew, rowptr, rank, cw);

    // layer 1
    k_agg16<<<NWB, 256, 0, stream>>>(xbHi, rowptr, cw, aggHi, aggLo);
    k_gemm1<<<GB, 256, 0, stream>>>(aggHi, aggLo, xbHi, xbLo, W1hi, W1lo, b1l,
                                    bn1g, bn1b, bn1m, bn1v, hHi, hLo);
    // layer 2 (+ fused lin3)
    k_agg16<<<NWB, 256, 0, stream>>>(hHi, rowptr, cw, aggHi, aggLo);
    k_gemm2<<<GB, 256, 0, stream>>>(aggHi, aggLo, hHi, hLo, W2hi, W2lo, b2l,
                                    bn2g, bn2b, bn2m, bn2v, w3l, w3r, t4);
    // layer 3 edge aggregate
    k_out<<<NWB, 256, 0, stream>>>(t4, rowptr, cw, b3l, out);
}

// Round 3
// 562.559 us; speedup vs baseline: 1.1725x; 1.0564x over previous
//
#include <hip/hip_runtime.h>
#include <math.h>

#define N_NODES 100000
#define N_EDGES 1600000
#define F_INF   128
#define HIDF    128

#define MLP_BLOCKS  2048
#define CAST_BLOCKS 12500                     // N*128/4/256
#define WP_BASE     (CAST_BLOCKS + MLP_BLOCKS) // 14548
#define FRONT_GRID  (WP_BASE + 256)            // + 2x128 wpack blocks

typedef __attribute__((ext_vector_type(8)))  short short8;
typedef __attribute__((ext_vector_type(16))) float floatx16;

__device__ __forceinline__ unsigned short f2bf(float f) {
    unsigned u = __float_as_uint(f);
    return (unsigned short)((u + 0x7FFFu + ((u >> 16) & 1u)) >> 16);
}
__device__ __forceinline__ float bf2f(unsigned short h) {
    return __uint_as_float((unsigned)h << 16);
}

// ---------------------------------------------------------------- FRONT (merged)
// Three independent jobs in one kernel so the ~70 us atomic-histogram wall
// (memory-side RMW, 51 MB write-through, <1% VALUBusy) absorbs the edge-MLP's
// VALU/MFMA work instead of serializing with it:
//   - blocks with bid%7==3 (first 2048 of them): edge MLP (wave = 32 edges)
//   - bid >= WP_BASE (256 blocks): weight packing for both layers
//   - everything else (12500 blocks): x -> bf16 hi/lo cast + degree atomic
// Whole-block role selection -> no lane divergence.
__global__ __launch_bounds__(256) void k_front(
        const float* __restrict__ x,
        unsigned short* __restrict__ xbHi, unsigned short* __restrict__ xbLo,
        const int* __restrict__ dst, int* __restrict__ deg,
        unsigned char* __restrict__ rank,
        const float* __restrict__ ea,
        const float* __restrict__ mw1, const float* __restrict__ mb1,
        const float* __restrict__ mw2, const float* __restrict__ mb2,
        float* __restrict__ ew,
        const float* __restrict__ w1l, const float* __restrict__ w1r,
        short* __restrict__ W1hi, short* __restrict__ W1lo,
        const float* __restrict__ w2l, const float* __restrict__ w2r,
        short* __restrict__ W2hi, short* __restrict__ W2lo) {
    const int bid = blockIdx.x;

    if (bid >= WP_BASE) {
        // ---- weight packing (2 x 128 blocks) ----
        const int wb  = bid - WP_BASE;                   // 0..255
        const int idx = (wb & 127) * 256 + threadIdx.x;  // 0..32767
        const float* Wl = (wb < 128) ? w1l : w2l;
        const float* Wr = (wb < 128) ? w1r : w2r;
        short* Whi = (wb < 128) ? W1hi : W2hi;
        short* Wlo = (wb < 128) ? W1lo : W2lo;
        const int j  = idx & 7;
        const int L  = (idx >> 3) & 63;
        const int cb = (idx >> 9) & 3;
        const int kb = (idx >> 11);
        const int k  = kb * 16 + (L >> 5) * 8 + j;
        const int n  = cb * 32 + (L & 31);
        const float a = (k < 128) ? Wl[k * 128 + n] : Wr[(k - 128) * 128 + n];
        const unsigned short hb = f2bf(a);
        Whi[idx] = (short)hb;
        Wlo[idx] = (short)f2bf(a - bf2f(hb));
        return;
    }

    const bool is_mlp = ((bid % 7) == 3) && (bid < 7 * MLP_BLOCKS);
    if (!is_mlp) {
        // ---- cast + degree ----
        // cast-index: bid minus the number of mlp blocks with id < bid (bijective -> [0,12500))
        const int c   = (bid < 4) ? 0 : min(MLP_BLOCKS, (bid - 4) / 7 + 1);
        const int gid = (bid - c) * 256 + (int)threadIdx.x;   // 0 .. 3.2M-1
        const int i   = gid * 4;                              // N*128 exactly
        const float4 v = *(const float4*)(x + i);
        ushort4 h, l;
        h.x = f2bf(v.x); l.x = f2bf(v.x - bf2f(h.x));
        h.y = f2bf(v.y); l.y = f2bf(v.y - bf2f(h.y));
        h.z = f2bf(v.z); l.z = f2bf(v.z - bf2f(h.z));
        h.w = f2bf(v.w); l.w = f2bf(v.w - bf2f(h.w));
        *(ushort4*)(xbHi + i) = h;
        *(ushort4*)(xbLo + i) = l;
        if ((gid & 1) == 0) {
            const int e = gid >> 1;                           // covers all 1.6M edges
            rank[e] = (unsigned char)atomicAdd(&deg[dst[e]], 1);
        }
        return;
    }

    // ---- edge MLP (wave = 32 edges; grid-stride over 8192 waves) ----
    const int lane = threadIdx.x & 63;
    const int cl   = lane & 31;
    const int half = lane >> 5;
    const int wid  = (bid / 7) * 4 + ((int)threadIdx.x >> 6);
    const int nw   = MLP_BLOCKS * 4;

    short8 bw[4];
    float  w2c[4];
#pragma unroll
    for (int cb = 0; cb < 4; ++cb) {
        const int n = cb * 32 + cl;
        short8 b;
        if (half == 0) {
#pragma unroll
            for (int j = 0; j < 8; ++j) b[j] = (short)f2bf(mw1[j * 128 + n]);
        } else {
            b[0] = (short)f2bf(mb1[n]);
#pragma unroll
            for (int j = 1; j < 8; ++j) b[j] = 0;
        }
        bw[cb] = b;
        w2c[cb] = mw2[n];
    }
    short8 Abias;
    Abias[0] = (short)0x3F80;
#pragma unroll
    for (int j = 1; j < 8; ++j) Abias[j] = 0;

    floatx16 czero;
#pragma unroll
    for (int r = 0; r < 16; ++r) czero[r] = 0.f;

    const float bias2 = mb2[0];

    for (int e0 = wid * 32; e0 < N_EDGES; e0 += nw * 32) {
        short8 Ah;
        if (half == 0) {
            const float4 a0 = *(const float4*)(ea + (size_t)(e0 + cl) * 8);
            const float4 a1 = *(const float4*)(ea + (size_t)(e0 + cl) * 8 + 4);
            Ah[0] = (short)f2bf(a0.x); Ah[1] = (short)f2bf(a0.y);
            Ah[2] = (short)f2bf(a0.z); Ah[3] = (short)f2bf(a0.w);
            Ah[4] = (short)f2bf(a1.x); Ah[5] = (short)f2bf(a1.y);
            Ah[6] = (short)f2bf(a1.z); Ah[7] = (short)f2bf(a1.w);
        } else {
            Ah = Abias;
        }

        float z[16];
#pragma unroll
        for (int r = 0; r < 16; ++r) z[r] = 0.f;

#pragma unroll
        for (int cb = 0; cb < 4; ++cb) {
            floatx16 acc = __builtin_amdgcn_mfma_f32_32x32x16_bf16(Ah, bw[cb], czero, 0, 0, 0);
#pragma unroll
            for (int r = 0; r < 16; ++r)
                z[r] = fmaf(fmaxf(acc[r], 0.f), w2c[cb], z[r]);
        }

#pragma unroll
        for (int m = 1; m <= 16; m <<= 1) {
#pragma unroll
            for (int r = 0; r < 16; ++r) z[r] += __shfl_xor(z[r], m, 64);
        }

        float zz = z[0];
#pragma unroll
        for (int r = 1; r < 16; ++r) zz = (cl == r) ? z[r] : zz;
        if (cl < 16) {
            const int row = (cl & 3) + 8 * (cl >> 2) + 4 * half;
            ew[e0 + row] = 1.f / (1.f + __expf(-(zz + bias2)));
        }
    }
}

// ---------------------------------------------------------------- CSR build
__global__ void k_scan1(const int* __restrict__ deg, int* __restrict__ incl,
                        int* __restrict__ bsum) {
    __shared__ int sm[1024];
    const int tid = threadIdx.x;
    const int gi  = blockIdx.x * 1024 + tid;
    int v = (gi < N_NODES) ? deg[gi] : 0;
    sm[tid] = v;
    __syncthreads();
    for (int off = 1; off < 1024; off <<= 1) {
        int t = (tid >= off) ? sm[tid - off] : 0;
        __syncthreads();
        sm[tid] += t;
        __syncthreads();
    }
    if (gi < N_NODES) incl[gi] = sm[tid];
    if (tid == 1023) bsum[blockIdx.x] = sm[1023];
}

// scan2 folded in: every block redundantly prefix-sums the 98 block sums
// (trivial LDS work) -> one fewer serializing dispatch.
__global__ void k_scan23(const int* __restrict__ incl, const int* __restrict__ bsum,
                         int* __restrict__ rowptr, int nb) {
    __shared__ int sm[128];
    const int tid = threadIdx.x;   // 256
    int v = 0;
    if (tid < 128) {
        v = (tid < nb) ? bsum[tid] : 0;
        sm[tid] = v;
    }
    __syncthreads();
    for (int off = 1; off < 128; off <<= 1) {
        int t = 0;
        if (tid < 128 && tid >= off) t = sm[tid - off];
        __syncthreads();
        if (tid < 128) sm[tid] += t;
        __syncthreads();
    }
    if (tid < 128) sm[tid] -= v;   // exclusive block offset
    __syncthreads();
    const int i = blockIdx.x * 256 + tid;
    if (i < N_NODES) rowptr[i + 1] = sm[i >> 10] + incl[i];
    if (i == 0) rowptr[0] = 0;
}

__global__ void k_fill(const int* __restrict__ src, const int* __restrict__ dst,
                       const float* __restrict__ ew, const int* __restrict__ rowptr,
                       const unsigned char* __restrict__ rank,
                       unsigned* __restrict__ cw) {
    int e = blockIdx.x * 256 + threadIdx.x;
    if (e < N_EDGES) {
        int d   = dst[e];
        int pos = rowptr[d] + (int)rank[e];
        unsigned wb = (unsigned)f2bf(ew[e]) & 0x7FFFu;
        cw[pos] = ((unsigned)src[e] << 15) | wb;
    }
}

// ---------------------------------------------------------------- aggregation (bf16 gather)
// Proven round-0 structure (wave per node, high occupancy); writes bf16 hi/lo.
__global__ __launch_bounds__(256) void k_agg16(
        const unsigned short* __restrict__ xb, const int* __restrict__ rowptr,
        const unsigned* __restrict__ cw,
        unsigned short* __restrict__ aggHi, unsigned short* __restrict__ aggLo) {
    const int lane = threadIdx.x & 63;
    const int half = lane >> 5;
    const int cl   = lane & 31;
    const int node = blockIdx.x * (blockDim.x >> 6) + (threadIdx.x >> 6);
    if (node >= N_NODES) return;
    const int s = rowptr[node], e = rowptr[node + 1];
    float a0 = 0.f, a1 = 0.f, a2 = 0.f, a3 = 0.f;

    for (int j0 = s; j0 < e; j0 += 8) {
        int ss[4]; float ww[4];
#pragma unroll
        for (int u = 0; u < 4; ++u) {
            const int j  = j0 + 2 * u + half;
            const int jc = min(j, e - 1);
            const unsigned p = cw[jc];
            ss[u] = (int)(p >> 15);
            ww[u] = (j < e) ? __uint_as_float((p & 0x7FFFu) << 16) : 0.f;
        }
        uint2 g[4];
#pragma unroll
        for (int u = 0; u < 4; ++u)
            g[u] = *(const uint2*)(xb + (size_t)ss[u] * 128 + cl * 4);
#pragma unroll
        for (int u = 0; u < 4; ++u) {
            const float f0 = __uint_as_float(g[u].x << 16);
            const float f1 = __uint_as_float(g[u].x & 0xFFFF0000u);
            const float f2 = __uint_as_float(g[u].y << 16);
            const float f3 = __uint_as_float(g[u].y & 0xFFFF0000u);
            a0 = fmaf(ww[u], f0, a0);
            a1 = fmaf(ww[u], f1, a1);
            a2 = fmaf(ww[u], f2, a2);
            a3 = fmaf(ww[u], f3, a3);
        }
    }
    a0 += __shfl_xor(a0, 32, 64);
    a1 += __shfl_xor(a1, 32, 64);
    a2 += __shfl_xor(a2, 32, 64);
    a3 += __shfl_xor(a3, 32, 64);
    if (half == 0) {
        const float inv = 1.f / fmaxf((float)(e - s), 1.f);
        a0 *= inv; a1 *= inv; a2 *= inv; a3 *= inv;
        ushort4 h, l;
        h.x = f2bf(a0); l.x = f2bf(a0 - bf2f(h.x));
        h.y = f2bf(a1); l.y = f2bf(a1 - bf2f(h.y));
        h.z = f2bf(a2); l.z = f2bf(a2 - bf2f(h.z));
        h.w = f2bf(a3); l.w = f2bf(a3 - bf2f(h.w));
        *(ushort4*)(aggHi + (size_t)node * 128 + cl * 4) = h;
        *(ushort4*)(aggLo + (size_t)node * 128 + cl * 4) = l;
    }
}

// ---------------------------------------------------------------- MFMA GEMM (both layers)
// Pre-split bf16 hi/lo A operands, K=256, 3 MFMA/frag; bn+relu -> bf16 hi/lo.
// Lean epilogue only (the lin3-fused variant cost 320 shfl/thread -> 97 us).
__global__ __launch_bounds__(256) void k_gemm(
    const unsigned short* __restrict__ AaggHi, const unsigned short* __restrict__ AaggLo,
    const unsigned short* __restrict__ AxHi, const unsigned short* __restrict__ AxLo,
    const short* __restrict__ Whi, const short* __restrict__ Wlo,
    const float* __restrict__ bl,
    const float* __restrict__ bng, const float* __restrict__ bnb,
    const float* __restrict__ bnm, const float* __restrict__ bnv,
    unsigned short* __restrict__ outHi, unsigned short* __restrict__ outLo) {
    const int tid  = threadIdx.x;
    const int lane = tid & 63;
    const int w    = tid >> 6;
    const int row0 = blockIdx.x * 128 + w * 32;
    const int rrow = lane & 31;
    const int kq   = lane >> 5;
    const int arow = min(row0 + rrow, N_NODES - 1);

    floatx16 acc[4];
#pragma unroll
    for (int cb = 0; cb < 4; ++cb)
#pragma unroll
        for (int r = 0; r < 16; ++r) acc[cb][r] = 0.f;

    const size_t abase = (size_t)arow * 128 + kq * 8;

#pragma unroll 2
    for (int kb = 0; kb < 16; ++kb) {
        const size_t ao = abase + (kb & 7) * 16;
        const short8 Ah = *(const short8*)(((kb < 8) ? AaggHi : AxHi) + ao);
        const short8 Al = *(const short8*)(((kb < 8) ? AaggLo : AxLo) + ao);
#pragma unroll
        for (int cb = 0; cb < 4; ++cb) {
            const size_t wo = ((size_t)(kb * 4 + cb) * 64 + lane) * 8;
            const short8 wh = *(const short8*)(Whi + wo);
            const short8 wl = *(const short8*)(Wlo + wo);
            acc[cb] = __builtin_amdgcn_mfma_f32_32x32x16_bf16(Ah, wh, acc[cb], 0, 0, 0);
            acc[cb] = __builtin_amdgcn_mfma_f32_32x32x16_bf16(Al, wh, acc[cb], 0, 0, 0);
            acc[cb] = __builtin_amdgcn_mfma_f32_32x32x16_bf16(Ah, wl, acc[cb], 0, 0, 0);
        }
    }

#pragma unroll
    for (int cb = 0; cb < 4; ++cb) {
        const int c = cb * 32 + (lane & 31);
        const float s = bng[c] * rsqrtf(bnv[c] + 1e-5f);
        const float t = (bl[c] - bnm[c]) * s + bnb[c];
#pragma unroll
        for (int r = 0; r < 16; ++r) {
            const int row = row0 + (r & 3) + 8 * (r >> 2) + 4 * kq;
            if (row < N_NODES) {
                const float v = fmaxf(fmaf(acc[cb][r], s, t), 0.f);
                const unsigned short hb = f2bf(v);
                outHi[(size_t)row * 128 + c] = hb;
                outLo[(size_t)row * 128 + c] = f2bf(v - bf2f(hb));
            }
        }
    }
}

// ---------------------------------------------------------------- layer 3 transform
// Reads the bf16 hi/lo pair (same operand the old fp32 path represented).
__global__ void k_lin3(const unsigned short* __restrict__ hHi,
                       const unsigned short* __restrict__ hLo,
                       const float* __restrict__ w3l,
                       const float* __restrict__ w3r, float* __restrict__ t4) {
    const int lane = threadIdx.x & 63;
    const int node = blockIdx.x * (blockDim.x >> 6) + (threadIdx.x >> 6);
    if (node >= N_NODES) return;
    const size_t b = (size_t)node * 128;
    const float h0 = bf2f(hHi[b + lane])      + bf2f(hLo[b + lane]);
    const float h1 = bf2f(hHi[b + 64 + lane]) + bf2f(hLo[b + 64 + lane]);
    const float2 wl0 = *(const float2*)(w3l + lane * 2);
    const float2 wl1 = *(const float2*)(w3l + (64 + lane) * 2);
    const float2 wr0 = *(const float2*)(w3r + lane * 2);
    const float2 wr1 = *(const float2*)(w3r + (64 + lane) * 2);
    float p0 = h0 * wl0.x + h1 * wl1.x;
    float p1 = h0 * wl0.y + h1 * wl1.y;
    float p2 = h0 * wr0.x + h1 * wr1.x;
    float p3 = h0 * wr0.y + h1 * wr1.y;
#pragma unroll
    for (int m = 1; m < 64; m <<= 1) {
        p0 += __shfl_xor(p0, m, 64);
        p1 += __shfl_xor(p1, m, 64);
        p2 += __shfl_xor(p2, m, 64);
        p3 += __shfl_xor(p3, m, 64);
    }
    if (lane == 0) {
        float4 o; o.x = p0; o.y = p1; o.z = p2; o.w = p3;
        *(float4*)(t4 + (size_t)node * 4) = o;
    }
}

// ---------------------------------------------------------------- final edge aggregate
__global__ void k_out(const float* __restrict__ t4, const int* __restrict__ rowptr,
                      const unsigned* __restrict__ cw,
                      const float* __restrict__ b3, float* __restrict__ out) {
    const int lane = threadIdx.x & 63;
    const int node = blockIdx.x * (blockDim.x >> 6) + (threadIdx.x >> 6);
    if (node >= N_NODES) return;
    const int s = rowptr[node], e = rowptr[node + 1];
    float a0 = 0.f, a1 = 0.f;
    for (int j = s + lane; j < e; j += 64) {
        const unsigned p = cw[j];
        const int   sr = (int)(p >> 15);
        const float w  = __uint_as_float((p & 0x7FFFu) << 16);
        float2 t = *(const float2*)(t4 + (size_t)sr * 4);
        a0 += w * t.x; a1 += w * t.y;
    }
#pragma unroll
    for (int m = 1; m < 64; m <<= 1) {
        a0 += __shfl_xor(a0, m, 64);
        a1 += __shfl_xor(a1, m, 64);
    }
    if (lane == 0) {
        float inv = 1.f / fmaxf((float)(e - s), 1.f);
        float2 o;
        o.x = a0 * inv + b3[0] + t4[(size_t)node * 4 + 2];
        o.y = a1 * inv + b3[1] + t4[(size_t)node * 4 + 3];
        *(float2*)(out + (size_t)node * 2) = o;
    }
}

// ---------------------------------------------------------------- launch
extern "C" void kernel_launch(void* const* d_in, const int* in_sizes, int n_in,
                              void* d_out, int out_size, void* d_ws, size_t ws_size,
                              hipStream_t stream) {
    const float* x    = (const float*)d_in[0];
    const float* ea   = (const float*)d_in[1];
    const int*   ei   = (const int*)d_in[2];
    const float* ew1w = (const float*)d_in[3];
    const float* ew1b = (const float*)d_in[4];
    const float* ew2w = (const float*)d_in[5];
    const float* ew2b = (const float*)d_in[6];
    const float* w1l  = (const float*)d_in[7];
    const float* b1l  = (const float*)d_in[8];
    const float* w1r  = (const float*)d_in[9];
    const float* w2l  = (const float*)d_in[10];
    const float* b2l  = (const float*)d_in[11];
    const float* w2r  = (const float*)d_in[12];
    const float* w3l  = (const float*)d_in[13];
    const float* b3l  = (const float*)d_in[14];
    const float* w3r  = (const float*)d_in[15];
    const float* bn1g = (const float*)d_in[16];
    const float* bn1b = (const float*)d_in[17];
    const float* bn1m = (const float*)d_in[18];
    const float* bn1v = (const float*)d_in[19];
    const float* bn2g = (const float*)d_in[20];
    const float* bn2b = (const float*)d_in[21];
    const float* bn2m = (const float*)d_in[22];
    const float* bn2v = (const float*)d_in[23];

    const int* src = ei;
    const int* dst = ei + N_EDGES;
    float* out = (float*)d_out;

    size_t off = 0;
    auto carve = [&](size_t bytes) -> void* {
        void* p = (char*)d_ws + off;
        off += (bytes + 255) & ~(size_t)255;
        return p;
    };
    float* ew     = (float*)carve((size_t)N_EDGES * 4);
    unsigned* cw  = (unsigned*)carve((size_t)N_EDGES * 4);
    unsigned char* rank = (unsigned char*)carve((size_t)N_EDGES);
    int*   rowptr = (int*)carve((size_t)(N_NODES + 1) * 4);
    int*   deg    = (int*)carve((size_t)N_NODES * 4);
    int*   bsum   = (int*)carve(128 * 4);
    int*   incl   = (int*)carve((size_t)N_NODES * 4);
    float* t4     = (float*)carve((size_t)N_NODES * 4 * 4);
    short* W1hi   = (short*)carve(32768 * 2);
    short* W1lo   = (short*)carve(32768 * 2);
    short* W2hi   = (short*)carve(32768 * 2);
    short* W2lo   = (short*)carve(32768 * 2);
    unsigned short* xbHi  = (unsigned short*)carve((size_t)N_NODES * 128 * 2);
    unsigned short* xbLo  = (unsigned short*)carve((size_t)N_NODES * 128 * 2);
    unsigned short* aggHi = (unsigned short*)carve((size_t)N_NODES * 128 * 2);
    unsigned short* aggLo = (unsigned short*)carve((size_t)N_NODES * 128 * 2);
    unsigned short* hHi   = (unsigned short*)carve((size_t)N_NODES * 128 * 2);
    unsigned short* hLo   = (unsigned short*)carve((size_t)N_NODES * 128 * 2);
    unsigned short* hBhi  = (unsigned short*)carve((size_t)N_NODES * 128 * 2);
    unsigned short* hBlo  = (unsigned short*)carve((size_t)N_NODES * 128 * 2);
    (void)ws_size; (void)n_in; (void)in_sizes; (void)out_size;

    hipMemsetAsync(deg, 0, (size_t)N_NODES * 4, stream);

    const int EB = (N_EDGES + 255) / 256;        // 6250
    const int NB_SCAN = (N_NODES + 1023) / 1024; // 98
    const int NWB = (N_NODES + 3) / 4;           // 25000
    const int GB = (N_NODES + 127) / 128;        // 782

    k_front<<<FRONT_GRID, 256, 0, stream>>>(
        x, xbHi, xbLo, dst, deg, rank,
        ea, ew1w, ew1b, ew2w, ew2b, ew,
        w1l, w1r, W1hi, W1lo, w2l, w2r, W2hi, W2lo);
    k_scan1<<<NB_SCAN, 1024, 0, stream>>>(deg, incl, bsum);
    k_scan23<<<(N_NODES + 255) / 256, 256, 0, stream>>>(incl, bsum, rowptr, NB_SCAN);
    k_fill<<<EB, 256, 0, stream>>>(src, dst, ew, rowptr, rank, cw);

    // layer 1
    k_agg16<<<NWB, 256, 0, stream>>>(xbHi, rowptr, cw, aggHi, aggLo);
    k_gemm<<<GB, 256, 0, stream>>>(aggHi, aggLo, xbHi, xbLo, W1hi, W1lo, b1l,
                                   bn1g, bn1b, bn1m, bn1v, hHi, hLo);
    // layer 2
    k_agg16<<<NWB, 256, 0, stream>>>(hHi, rowptr, cw, aggHi, aggLo);
    k_gemm<<<GB, 256, 0, stream>>>(aggHi, aggLo, hHi, hLo, W2hi, W2lo, b2l,
                                   bn2g, bn2b, bn2m, bn2v, hBhi, hBlo);
    // layer 3
    k_lin3<<<NWB, 256, 0, stream>>>(hBhi, hBlo, w3l, w3r, t4);
    k_out<<<NWB, 256, 0, stream>>>(t4, rowptr, cw, b3l, out);
}

// Round 4
// 525.698 us; speedup vs baseline: 1.2547x; 1.0701x over previous
//
#include <hip/hip_runtime.h>
#include <math.h>

#define N_NODES 100000
#define N_EDGES 1600000
#define F_INF   128
#define HIDF    128

#define MLP_BLOCKS  2048
#define CAST_BLOCKS 12500                     // N*128/4/256
#define WP_BASE     (CAST_BLOCKS + MLP_BLOCKS) // 14548
#define FRONT_GRID  (WP_BASE + 256)            // + 2x128 wpack blocks

typedef __attribute__((ext_vector_type(8)))  short short8;
typedef __attribute__((ext_vector_type(16))) float floatx16;

__device__ __forceinline__ unsigned short f2bf(float f) {
    unsigned u = __float_as_uint(f);
    return (unsigned short)((u + 0x7FFFu + ((u >> 16) & 1u)) >> 16);
}
__device__ __forceinline__ float bf2f(unsigned short h) {
    return __uint_as_float((unsigned)h << 16);
}

// ---------------------------------------------------------------- FRONT (merged)
// cast+degree-atomic / edge-MLP / weight-pack in one kernel so the atomic
// histogram wall absorbs the other front work (proven round 3: -30 us).
__global__ __launch_bounds__(256) void k_front(
        const float* __restrict__ x,
        unsigned short* __restrict__ xbHi, unsigned short* __restrict__ xbLo,
        const int* __restrict__ dst, int* __restrict__ deg,
        unsigned char* __restrict__ rank,
        const float* __restrict__ ea,
        const float* __restrict__ mw1, const float* __restrict__ mb1,
        const float* __restrict__ mw2, const float* __restrict__ mb2,
        float* __restrict__ ew,
        const float* __restrict__ w1l, const float* __restrict__ w1r,
        short* __restrict__ W1hi, short* __restrict__ W1lo,
        const float* __restrict__ w2l, const float* __restrict__ w2r,
        short* __restrict__ W2hi, short* __restrict__ W2lo) {
    const int bid = blockIdx.x;

    if (bid >= WP_BASE) {
        // ---- weight packing (2 x 128 blocks) ----
        const int wb  = bid - WP_BASE;                   // 0..255
        const int idx = (wb & 127) * 256 + threadIdx.x;  // 0..32767
        const float* Wl = (wb < 128) ? w1l : w2l;
        const float* Wr = (wb < 128) ? w1r : w2r;
        short* Whi = (wb < 128) ? W1hi : W2hi;
        short* Wlo = (wb < 128) ? W1lo : W2lo;
        const int j  = idx & 7;
        const int L  = (idx >> 3) & 63;
        const int cb = (idx >> 9) & 3;
        const int kb = (idx >> 11);
        const int k  = kb * 16 + (L >> 5) * 8 + j;
        const int n  = cb * 32 + (L & 31);
        const float a = (k < 128) ? Wl[k * 128 + n] : Wr[(k - 128) * 128 + n];
        const unsigned short hb = f2bf(a);
        Whi[idx] = (short)hb;
        Wlo[idx] = (short)f2bf(a - bf2f(hb));
        return;
    }

    const bool is_mlp = ((bid % 7) == 3) && (bid < 7 * MLP_BLOCKS);
    if (!is_mlp) {
        // ---- cast + degree ----
        const int c   = (bid < 4) ? 0 : min(MLP_BLOCKS, (bid - 4) / 7 + 1);
        const int gid = (bid - c) * 256 + (int)threadIdx.x;   // 0 .. 3.2M-1
        const int i   = gid * 4;                              // N*128 exactly
        const float4 v = *(const float4*)(x + i);
        ushort4 h, l;
        h.x = f2bf(v.x); l.x = f2bf(v.x - bf2f(h.x));
        h.y = f2bf(v.y); l.y = f2bf(v.y - bf2f(h.y));
        h.z = f2bf(v.z); l.z = f2bf(v.z - bf2f(h.z));
        h.w = f2bf(v.w); l.w = f2bf(v.w - bf2f(h.w));
        *(ushort4*)(xbHi + i) = h;
        *(ushort4*)(xbLo + i) = l;
        if ((gid & 1) == 0) {
            const int e = gid >> 1;                           // covers all 1.6M edges
            rank[e] = (unsigned char)atomicAdd(&deg[dst[e]], 1);
        }
        return;
    }

    // ---- edge MLP (wave = 32 edges; grid-stride over 8192 waves) ----
    const int lane = threadIdx.x & 63;
    const int cl   = lane & 31;
    const int half = lane >> 5;
    const int wid  = (bid / 7) * 4 + ((int)threadIdx.x >> 6);
    const int nw   = MLP_BLOCKS * 4;

    short8 bw[4];
    float  w2c[4];
#pragma unroll
    for (int cb = 0; cb < 4; ++cb) {
        const int n = cb * 32 + cl;
        short8 b;
        if (half == 0) {
#pragma unroll
            for (int j = 0; j < 8; ++j) b[j] = (short)f2bf(mw1[j * 128 + n]);
        } else {
            b[0] = (short)f2bf(mb1[n]);
#pragma unroll
            for (int j = 1; j < 8; ++j) b[j] = 0;
        }
        bw[cb] = b;
        w2c[cb] = mw2[n];
    }
    short8 Abias;
    Abias[0] = (short)0x3F80;
#pragma unroll
    for (int j = 1; j < 8; ++j) Abias[j] = 0;

    floatx16 czero;
#pragma unroll
    for (int r = 0; r < 16; ++r) czero[r] = 0.f;

    const float bias2 = mb2[0];

    for (int e0 = wid * 32; e0 < N_EDGES; e0 += nw * 32) {
        short8 Ah;
        if (half == 0) {
            const float4 a0 = *(const float4*)(ea + (size_t)(e0 + cl) * 8);
            const float4 a1 = *(const float4*)(ea + (size_t)(e0 + cl) * 8 + 4);
            Ah[0] = (short)f2bf(a0.x); Ah[1] = (short)f2bf(a0.y);
            Ah[2] = (short)f2bf(a0.z); Ah[3] = (short)f2bf(a0.w);
            Ah[4] = (short)f2bf(a1.x); Ah[5] = (short)f2bf(a1.y);
            Ah[6] = (short)f2bf(a1.z); Ah[7] = (short)f2bf(a1.w);
        } else {
            Ah = Abias;
        }

        float z[16];
#pragma unroll
        for (int r = 0; r < 16; ++r) z[r] = 0.f;

#pragma unroll
        for (int cb = 0; cb < 4; ++cb) {
            floatx16 acc = __builtin_amdgcn_mfma_f32_32x32x16_bf16(Ah, bw[cb], czero, 0, 0, 0);
#pragma unroll
            for (int r = 0; r < 16; ++r)
                z[r] = fmaf(fmaxf(acc[r], 0.f), w2c[cb], z[r]);
        }

#pragma unroll
        for (int m = 1; m <= 16; m <<= 1) {
#pragma unroll
            for (int r = 0; r < 16; ++r) z[r] += __shfl_xor(z[r], m, 64);
        }

        float zz = z[0];
#pragma unroll
        for (int r = 1; r < 16; ++r) zz = (cl == r) ? z[r] : zz;
        if (cl < 16) {
            const int row = (cl & 3) + 8 * (cl >> 2) + 4 * half;
            ew[e0 + row] = 1.f / (1.f + __expf(-(zz + bias2)));
        }
    }
}

// ---------------------------------------------------------------- CSR build
__global__ void k_scan1(const int* __restrict__ deg, int* __restrict__ incl,
                        int* __restrict__ bsum) {
    __shared__ int sm[1024];
    const int tid = threadIdx.x;
    const int gi  = blockIdx.x * 1024 + tid;
    int v = (gi < N_NODES) ? deg[gi] : 0;
    sm[tid] = v;
    __syncthreads();
    for (int off = 1; off < 1024; off <<= 1) {
        int t = (tid >= off) ? sm[tid - off] : 0;
        __syncthreads();
        sm[tid] += t;
        __syncthreads();
    }
    if (gi < N_NODES) incl[gi] = sm[tid];
    if (tid == 1023) bsum[blockIdx.x] = sm[1023];
}

__global__ void k_scan23(const int* __restrict__ incl, const int* __restrict__ bsum,
                         int* __restrict__ rowptr, int nb) {
    __shared__ int sm[128];
    const int tid = threadIdx.x;   // 256
    int v = 0;
    if (tid < 128) {
        v = (tid < nb) ? bsum[tid] : 0;
        sm[tid] = v;
    }
    __syncthreads();
    for (int off = 1; off < 128; off <<= 1) {
        int t = 0;
        if (tid < 128 && tid >= off) t = sm[tid - off];
        __syncthreads();
        if (tid < 128) sm[tid] += t;
        __syncthreads();
    }
    if (tid < 128) sm[tid] -= v;   // exclusive block offset
    __syncthreads();
    const int i = blockIdx.x * 256 + tid;
    if (i < N_NODES) rowptr[i + 1] = sm[i >> 10] + incl[i];
    if (i == 0) rowptr[0] = 0;
}

__global__ void k_fill(const int* __restrict__ src, const int* __restrict__ dst,
                       const float* __restrict__ ew, const int* __restrict__ rowptr,
                       const unsigned char* __restrict__ rank,
                       unsigned* __restrict__ cw) {
    int e = blockIdx.x * 256 + threadIdx.x;
    if (e < N_EDGES) {
        int d   = dst[e];
        int pos = rowptr[d] + (int)rank[e];
        unsigned wb = (unsigned)f2bf(ew[e]) & 0x7FFFu;
        cw[pos] = ((unsigned)src[e] << 15) | wb;
    }
}

// ---------------------------------------------------------------- aggregation (bf16 gather)
// Proven structure (wave per node, high occupancy); writes bf16 hi/lo.
__global__ __launch_bounds__(256) void k_agg16(
        const unsigned short* __restrict__ xb, const int* __restrict__ rowptr,
        const unsigned* __restrict__ cw,
        unsigned short* __restrict__ aggHi, unsigned short* __restrict__ aggLo) {
    const int lane = threadIdx.x & 63;
    const int half = lane >> 5;
    const int cl   = lane & 31;
    const int node = blockIdx.x * (blockDim.x >> 6) + (threadIdx.x >> 6);
    if (node >= N_NODES) return;
    const int s = rowptr[node], e = rowptr[node + 1];
    float a0 = 0.f, a1 = 0.f, a2 = 0.f, a3 = 0.f;

    for (int j0 = s; j0 < e; j0 += 8) {
        int ss[4]; float ww[4];
#pragma unroll
        for (int u = 0; u < 4; ++u) {
            const int j  = j0 + 2 * u + half;
            const int jc = min(j, e - 1);
            const unsigned p = cw[jc];
            ss[u] = (int)(p >> 15);
            ww[u] = (j < e) ? __uint_as_float((p & 0x7FFFu) << 16) : 0.f;
        }
        uint2 g[4];
#pragma unroll
        for (int u = 0; u < 4; ++u)
            g[u] = *(const uint2*)(xb + (size_t)ss[u] * 128 + cl * 4);
#pragma unroll
        for (int u = 0; u < 4; ++u) {
            const float f0 = __uint_as_float(g[u].x << 16);
            const float f1 = __uint_as_float(g[u].x & 0xFFFF0000u);
            const float f2 = __uint_as_float(g[u].y << 16);
            const float f3 = __uint_as_float(g[u].y & 0xFFFF0000u);
            a0 = fmaf(ww[u], f0, a0);
            a1 = fmaf(ww[u], f1, a1);
            a2 = fmaf(ww[u], f2, a2);
            a3 = fmaf(ww[u], f3, a3);
        }
    }
    a0 += __shfl_xor(a0, 32, 64);
    a1 += __shfl_xor(a1, 32, 64);
    a2 += __shfl_xor(a2, 32, 64);
    a3 += __shfl_xor(a3, 32, 64);
    if (half == 0) {
        const float inv = 1.f / fmaxf((float)(e - s), 1.f);
        a0 *= inv; a1 *= inv; a2 *= inv; a3 *= inv;
        ushort4 h, l;
        h.x = f2bf(a0); l.x = f2bf(a0 - bf2f(h.x));
        h.y = f2bf(a1); l.y = f2bf(a1 - bf2f(h.y));
        h.z = f2bf(a2); l.z = f2bf(a2 - bf2f(h.z));
        h.w = f2bf(a3); l.w = f2bf(a3 - bf2f(h.w));
        *(ushort4*)(aggHi + (size_t)node * 128 + cl * 4) = h;
        *(ushort4*)(aggLo + (size_t)node * 128 + cl * 4) = l;
    }
}

// ---------------------------------------------------------------- MFMA GEMM (LDS-staged A)
// Round-2/3 direct-load version was latency-bound (MfmaUtil 7.6%, VALUBusy 5%,
// HBM 7% — all idle): per-lane A-frag loads are 16B at 256B lane stride = 32
// scattered transactions per wave-instr, dependent-chained into the MFMAs at
// ~3 waves/SIMD. Fix: 32 rows/block (grid 3125, exact), 4 waves = 4 col-blocks.
// A-slab staged to LDS via full-row 256B contiguous bursts (8 thr/row x 32B);
// fragments then read from LDS with the round-1-verified XOR swizzle
// (slot ^ (row&15), 16B slots). Root-half global loads are issued BEFORE the
// agg-half MFMA phase (issue-early/write-late) so HBM latency hides under
// compute. acc = 16 AGPR, LDS = 16 KB -> ~8 blocks/CU resident.
__global__ __launch_bounds__(256) void k_gemm(
    const unsigned short* __restrict__ AaggHi, const unsigned short* __restrict__ AaggLo,
    const unsigned short* __restrict__ AxHi, const unsigned short* __restrict__ AxLo,
    const short* __restrict__ Whi, const short* __restrict__ Wlo,
    const float* __restrict__ bl,
    const float* __restrict__ bng, const float* __restrict__ bnb,
    const float* __restrict__ bnm, const float* __restrict__ bnv,
    unsigned short* __restrict__ outHi, unsigned short* __restrict__ outLo) {
    __shared__ unsigned short SH[32 * 128];   // hi plane, swizzled 16B slots
    __shared__ unsigned short SL[32 * 128];   // lo plane
    const int tid  = threadIdx.x;
    const int lane = tid & 63;
    const int cb   = tid >> 6;                // wave = column-block
    const int rrow = lane & 31;
    const int kq   = lane >> 5;
    const int row0 = blockIdx.x * 32;         // 3125*32 == N_NODES exactly

    // staging coords: 8 threads/row, 16 shorts (32B) each
    const int sr = tid >> 3;                  // 0..31
    const int sc = (tid & 7) * 16;            // 0,16,..,112
    const int s0 = sc >> 3;                   // even slot index
    const size_t gsrc = (size_t)(row0 + sr) * 128 + sc;
    const int ld0 = sr * 128 + ((s0 + 0) ^ (sr & 15)) * 8;
    const int ld1 = sr * 128 + ((s0 + 1) ^ (sr & 15)) * 8;

    // issue agg loads, then root loads (all in flight), then LDS-write agg
    const uint4 ah0 = *(const uint4*)(AaggHi + gsrc);
    const uint4 ah1 = *(const uint4*)(AaggHi + gsrc + 8);
    const uint4 al0 = *(const uint4*)(AaggLo + gsrc);
    const uint4 al1 = *(const uint4*)(AaggLo + gsrc + 8);
    const uint4 rh0 = *(const uint4*)(AxHi + gsrc);
    const uint4 rh1 = *(const uint4*)(AxHi + gsrc + 8);
    const uint4 rl0 = *(const uint4*)(AxLo + gsrc);
    const uint4 rl1 = *(const uint4*)(AxLo + gsrc + 8);

    *(uint4*)(SH + ld0) = ah0;
    *(uint4*)(SH + ld1) = ah1;
    *(uint4*)(SL + ld0) = al0;
    *(uint4*)(SL + ld1) = al1;

    floatx16 acc;
#pragma unroll
    for (int r = 0; r < 16; ++r) acc[r] = 0.f;

    __syncthreads();

    // ---- agg half: K = 0..127 ----
#pragma unroll
    for (int kb = 0; kb < 8; ++kb) {
        const int slot = (2 * kb + kq) ^ (rrow & 15);
        const short8 Ah = *(const short8*)(SH + rrow * 128 + slot * 8);
        const short8 Al = *(const short8*)(SL + rrow * 128 + slot * 8);
        const size_t wo = ((size_t)(kb * 4 + cb) * 64 + lane) * 8;
        const short8 wh = *(const short8*)(Whi + wo);
        const short8 wl = *(const short8*)(Wlo + wo);
        acc = __builtin_amdgcn_mfma_f32_32x32x16_bf16(Ah, wh, acc, 0, 0, 0);
        acc = __builtin_amdgcn_mfma_f32_32x32x16_bf16(Al, wh, acc, 0, 0, 0);
        acc = __builtin_amdgcn_mfma_f32_32x32x16_bf16(Ah, wl, acc, 0, 0, 0);
    }

    __syncthreads();
    *(uint4*)(SH + ld0) = rh0;
    *(uint4*)(SH + ld1) = rh1;
    *(uint4*)(SL + ld0) = rl0;
    *(uint4*)(SL + ld1) = rl1;
    __syncthreads();

    // ---- root half: K = 128..255 ----
#pragma unroll
    for (int kb = 0; kb < 8; ++kb) {
        const int slot = (2 * kb + kq) ^ (rrow & 15);
        const short8 Ah = *(const short8*)(SH + rrow * 128 + slot * 8);
        const short8 Al = *(const short8*)(SL + rrow * 128 + slot * 8);
        const size_t wo = ((size_t)((kb + 8) * 4 + cb) * 64 + lane) * 8;
        const short8 wh = *(const short8*)(Whi + wo);
        const short8 wl = *(const short8*)(Wlo + wo);
        acc = __builtin_amdgcn_mfma_f32_32x32x16_bf16(Ah, wh, acc, 0, 0, 0);
        acc = __builtin_amdgcn_mfma_f32_32x32x16_bf16(Al, wh, acc, 0, 0, 0);
        acc = __builtin_amdgcn_mfma_f32_32x32x16_bf16(Ah, wl, acc, 0, 0, 0);
    }

    // ---- epilogue: bn + relu -> bf16 hi/lo ----
    const int c = cb * 32 + rrow;
    const float s = bng[c] * rsqrtf(bnv[c] + 1e-5f);
    const float t = (bl[c] - bnm[c]) * s + bnb[c];
#pragma unroll
    for (int r = 0; r < 16; ++r) {
        const int row = row0 + (r & 3) + 8 * (r >> 2) + 4 * kq;
        const float v = fmaxf(fmaf(acc[r], s, t), 0.f);
        const unsigned short hb = f2bf(v);
        outHi[(size_t)row * 128 + c] = hb;
        outLo[(size_t)row * 128 + c] = f2bf(v - bf2f(hb));
    }
}

// ---------------------------------------------------------------- layer 3 transform
__global__ void k_lin3(const unsigned short* __restrict__ hHi,
                       const unsigned short* __restrict__ hLo,
                       const float* __restrict__ w3l,
                       const float* __restrict__ w3r, float* __restrict__ t4) {
    const int lane = threadIdx.x & 63;
    const int node = blockIdx.x * (blockDim.x >> 6) + (threadIdx.x >> 6);
    if (node >= N_NODES) return;
    const size_t b = (size_t)node * 128;
    const float h0 = bf2f(hHi[b + lane])      + bf2f(hLo[b + lane]);
    const float h1 = bf2f(hHi[b + 64 + lane]) + bf2f(hLo[b + 64 + lane]);
    const float2 wl0 = *(const float2*)(w3l + lane * 2);
    const float2 wl1 = *(const float2*)(w3l + (64 + lane) * 2);
    const float2 wr0 = *(const float2*)(w3r + lane * 2);
    const float2 wr1 = *(const float2*)(w3r + (64 + lane) * 2);
    float p0 = h0 * wl0.x + h1 * wl1.x;
    float p1 = h0 * wl0.y + h1 * wl1.y;
    float p2 = h0 * wr0.x + h1 * wr1.x;
    float p3 = h0 * wr0.y + h1 * wr1.y;
#pragma unroll
    for (int m = 1; m < 64; m <<= 1) {
        p0 += __shfl_xor(p0, m, 64);
        p1 += __shfl_xor(p1, m, 64);
        p2 += __shfl_xor(p2, m, 64);
        p3 += __shfl_xor(p3, m, 64);
    }
    if (lane == 0) {
        float4 o; o.x = p0; o.y = p1; o.z = p2; o.w = p3;
        *(float4*)(t4 + (size_t)node * 4) = o;
    }
}

// ---------------------------------------------------------------- final edge aggregate
__global__ void k_out(const float* __restrict__ t4, const int* __restrict__ rowptr,
                      const unsigned* __restrict__ cw,
                      const float* __restrict__ b3, float* __restrict__ out) {
    const int lane = threadIdx.x & 63;
    const int node = blockIdx.x * (blockDim.x >> 6) + (threadIdx.x >> 6);
    if (node >= N_NODES) return;
    const int s = rowptr[node], e = rowptr[node + 1];
    float a0 = 0.f, a1 = 0.f;
    for (int j = s + lane; j < e; j += 64) {
        const unsigned p = cw[j];
        const int   sr = (int)(p >> 15);
        const float w  = __uint_as_float((p & 0x7FFFu) << 16);
        float2 t = *(const float2*)(t4 + (size_t)sr * 4);
        a0 += w * t.x; a1 += w * t.y;
    }
#pragma unroll
    for (int m = 1; m < 64; m <<= 1) {
        a0 += __shfl_xor(a0, m, 64);
        a1 += __shfl_xor(a1, m, 64);
    }
    if (lane == 0) {
        float inv = 1.f / fmaxf((float)(e - s), 1.f);
        float2 o;
        o.x = a0 * inv + b3[0] + t4[(size_t)node * 4 + 2];
        o.y = a1 * inv + b3[1] + t4[(size_t)node * 4 + 3];
        *(float2*)(out + (size_t)node * 2) = o;
    }
}

// ---------------------------------------------------------------- launch
extern "C" void kernel_launch(void* const* d_in, const int* in_sizes, int n_in,
                              void* d_out, int out_size, void* d_ws, size_t ws_size,
                              hipStream_t stream) {
    const float* x    = (const float*)d_in[0];
    const float* ea   = (const float*)d_in[1];
    const int*   ei   = (const int*)d_in[2];
    const float* ew1w = (const float*)d_in[3];
    const float* ew1b = (const float*)d_in[4];
    const float* ew2w = (const float*)d_in[5];
    const float* ew2b = (const float*)d_in[6];
    const float* w1l  = (const float*)d_in[7];
    const float* b1l  = (const float*)d_in[8];
    const float* w1r  = (const float*)d_in[9];
    const float* w2l  = (const float*)d_in[10];
    const float* b2l  = (const float*)d_in[11];
    const float* w2r  = (const float*)d_in[12];
    const float* w3l  = (const float*)d_in[13];
    const float* b3l  = (const float*)d_in[14];
    const float* w3r  = (const float*)d_in[15];
    const float* bn1g = (const float*)d_in[16];
    const float* bn1b = (const float*)d_in[17];
    const float* bn1m = (const float*)d_in[18];
    const float* bn1v = (const float*)d_in[19];
    const float* bn2g = (const float*)d_in[20];
    const float* bn2b = (const float*)d_in[21];
    const float* bn2m = (const float*)d_in[22];
    const float* bn2v = (const float*)d_in[23];

    const int* src = ei;
    const int* dst = ei + N_EDGES;
    float* out = (float*)d_out;

    size_t off = 0;
    auto carve = [&](size_t bytes) -> void* {
        void* p = (char*)d_ws + off;
        off += (bytes + 255) & ~(size_t)255;
        return p;
    };
    float* ew     = (float*)carve((size_t)N_EDGES * 4);
    unsigned* cw  = (unsigned*)carve((size_t)N_EDGES * 4);
    unsigned char* rank = (unsigned char*)carve((size_t)N_EDGES);
    int*   rowptr = (int*)carve((size_t)(N_NODES + 1) * 4);
    int*   deg    = (int*)carve((size_t)N_NODES * 4);
    int*   bsum   = (int*)carve(128 * 4);
    int*   incl   = (int*)carve((size_t)N_NODES * 4);
    float* t4     = (float*)carve((size_t)N_NODES * 4 * 4);
    short* W1hi   = (short*)carve(32768 * 2);
    short* W1lo   = (short*)carve(32768 * 2);
    short* W2hi   = (short*)carve(32768 * 2);
    short* W2lo   = (short*)carve(32768 * 2);
    unsigned short* xbHi  = (unsigned short*)carve((size_t)N_NODES * 128 * 2);
    unsigned short* xbLo  = (unsigned short*)carve((size_t)N_NODES * 128 * 2);
    unsigned short* aggHi = (unsigned short*)carve((size_t)N_NODES * 128 * 2);
    unsigned short* aggLo = (unsigned short*)carve((size_t)N_NODES * 128 * 2);
    unsigned short* hHi   = (unsigned short*)carve((size_t)N_NODES * 128 * 2);
    unsigned short* hLo   = (unsigned short*)carve((size_t)N_NODES * 128 * 2);
    unsigned short* hBhi  = (unsigned short*)carve((size_t)N_NODES * 128 * 2);
    unsigned short* hBlo  = (unsigned short*)carve((size_t)N_NODES * 128 * 2);
    (void)ws_size; (void)n_in; (void)in_sizes; (void)out_size;

    hipMemsetAsync(deg, 0, (size_t)N_NODES * 4, stream);

    const int EB = (N_EDGES + 255) / 256;        // 6250
    const int NB_SCAN = (N_NODES + 1023) / 1024; // 98
    const int NWB = (N_NODES + 3) / 4;           // 25000
    const int GB = N_NODES / 32;                 // 3125 (exact)

    k_front<<<FRONT_GRID, 256, 0, stream>>>(
        x, xbHi, xbLo, dst, deg, rank,
        ea, ew1w, ew1b, ew2w, ew2b, ew,
        w1l, w1r, W1hi, W1lo, w2l, w2r, W2hi, W2lo);
    k_scan1<<<NB_SCAN, 1024, 0, stream>>>(deg, incl, bsum);
    k_scan23<<<(N_NODES + 255) / 256, 256, 0, stream>>>(incl, bsum, rowptr, NB_SCAN);
    k_fill<<<EB, 256, 0, stream>>>(src, dst, ew, rowptr, rank, cw);

    // layer 1
    k_agg16<<<NWB, 256, 0, stream>>>(xbHi, rowptr, cw, aggHi, aggLo);
    k_gemm<<<GB, 256, 0, stream>>>(aggHi, aggLo, xbHi, xbLo, W1hi, W1lo, b1l,
                                   bn1g, bn1b, bn1m, bn1v, hHi, hLo);
    // layer 2
    k_agg16<<<NWB, 256, 0, stream>>>(hHi, rowptr, cw, aggHi, aggLo);
    k_gemm<<<GB, 256, 0, stream>>>(aggHi, aggLo, hHi, hLo, W2hi, W2lo, b2l,
                                   bn2g, bn2b, bn2m, bn2v, hBhi, hBlo);
    // layer 3
    k_lin3<<<NWB, 256, 0, stream>>>(hBhi, hBlo, w3l, w3r, t4);
    k_out<<<NWB, 256, 0, stream>>>(t4, rowptr, cw, b3l, out);
}